// Round 6
// baseline (539.478 us; speedup 1.0000x reference)
//
#include <hip/hip_runtime.h>

typedef unsigned short u16;
typedef unsigned char u8;
typedef unsigned int u32;
using s16x8 = __attribute__((ext_vector_type(8))) short;
using s16x4 = __attribute__((ext_vector_type(4))) short;
using f32x4 = __attribute__((ext_vector_type(4))) float;

#define DEV static __device__ __forceinline__

DEV float b2f(u16 u) { return __uint_as_float(((u32)u) << 16); }
DEV u16 f2bu(float f) {               // f32 -> bf16 bits, round-to-nearest-even
    u32 u = __float_as_uint(f);
    u32 r = (u + 0x7FFFu + ((u >> 16) & 1u)) >> 16;
    return (u16)r;
}
DEV float sigm(float x) { return 1.0f / (1.0f + expf(-x)); }

DEV float ldv(const void* p, int i, int f32flag) {
    if (f32flag) return ((const float*)p)[i];
    return b2f(((const u16*)p)[i]);
}
DEV void stv(void* p, int i, float v, int f32flag) {
    if (f32flag) ((float*)p)[i] = v;
    else ((u16*)p)[i] = f2bu(v);
}

DEV int lower_bound(const int* b, int n, int v) {
    int lo = 0, hi = n;
    while (lo < hi) { int mid = (lo + hi) >> 1; if (b[mid] < v) lo = mid + 1; else hi = mid; }
    return lo;
}

// identifier-named kernel from the stub skeleton (kept; harmless)
__global__ void DMPNN_Change_678604832935_kernel(int* p) {
    if (p && threadIdx.x == 0 && blockIdx.x == 0) p[0] = 1;
}

// ---- dtype sniffer ----
__global__ void detect_kernel(const void* x, int* flag) {
    __shared__ int cnt[128];
    int tid = threadIdx.x;
    if (tid < 128) {
        u16 v = ((const u16*)x)[tid];
        int e = (v >> 7) & 0xFF;
        cnt[tid] = (e >= 100 && e <= 141) ? 1 : 0;
    }
    __syncthreads();
    if (tid == 0) {
        int s = 0;
        for (int i = 0; i < 128; ++i) s += cnt[i];
        flag[0] = (s < 110) ? 1 : 0;   // 1 = float32 data, 0 = bf16 data
    }
}

__global__ void fillv_kernel(void* out, const int* flag, float v) {
    int i = blockIdx.x * 256 + threadIdx.x;
    if (i < 512) stv(out, i, v, flag[0]);
}

__global__ void zero_kernel(float* p, int n) {
    int i = blockIdx.x * 256 + threadIdx.x;
    int stride = gridDim.x * 256;
    for (; i < n; i += stride) p[i] = 0.0f;
}

// ---- counting sort of edges by dst: histogram -> scan -> scatter ----
__global__ void hist_kernel(const int* __restrict__ eidx, u32* __restrict__ cnt) {
    int i = blockIdx.x * 256 + threadIdx.x;
    if (i < 480000) atomicAdd(&cnt[eidx[480000 + i]], 1u);
}

__global__ void scan1_kernel(const u32* __restrict__ cnt, u32* __restrict__ part) {
    __shared__ u32 s[256];
    int i = blockIdx.x * 256 + threadIdx.x;
    s[threadIdx.x] = (i < 30000) ? cnt[i] : 0u;
    __syncthreads();
    for (int st = 128; st > 0; st >>= 1) {
        if (threadIdx.x < st) s[threadIdx.x] += s[threadIdx.x + st];
        __syncthreads();
    }
    if (threadIdx.x == 0) part[blockIdx.x] = s[0];
}

// wave-parallel exclusive scan of <=128 partials (was a 1-thread serial loop)
__global__ void scan2_kernel(const u32* __restrict__ part, u32* __restrict__ pexcl, int nb) {
    int tid = threadIdx.x;              // blockDim = 128
    u32 v = (tid < nb) ? part[tid] : 0u;
    u32 x = v;
    #pragma unroll
    for (int off = 1; off < 64; off <<= 1) {
        u32 t = __shfl_up(x, off, 64);
        if ((tid & 63) >= off) x += t;
    }
    __shared__ u32 wsum;
    if (tid == 63) wsum = x;
    __syncthreads();
    u32 add = (tid >= 64) ? wsum : 0u;
    if (tid < nb) pexcl[tid] = x + add - v;   // exclusive
}

__global__ void scan3_kernel(u32* __restrict__ cursor, const u32* __restrict__ pexcl) {
    __shared__ u32 s[256];
    int b = blockIdx.x, tid = threadIdx.x;
    int i = b * 256 + tid;
    u32 v = (i < 30000) ? cursor[i] : 0u;
    s[tid] = v;
    __syncthreads();
    for (int off = 1; off < 256; off <<= 1) {
        u32 t = (tid >= off) ? s[tid - off] : 0u;
        __syncthreads();
        s[tid] += t;
        __syncthreads();
    }
    u32 excl = s[tid] - v + pexcl[b];
    if (i < 30000) cursor[i] = excl;
}

__global__ void scatter_kernel(const int* __restrict__ eidx, u32* __restrict__ cursor,
                               u16* __restrict__ permLo, u8* __restrict__ permHi) {
    int i = blockIdx.x * 256 + threadIdx.x;
    if (i < 480000) {
        int d = eidx[480000 + i];
        u32 pos = atomicAdd(&cursor[d], 1u);
        permLo[pos] = (u16)(i & 0xFFFF);
        permHi[pos] = (u8)(i >> 16);
    }
}

// after scatter, cursor[d] = inclusive end index of segment d -> deg
__global__ void deg_kernel(const u32* __restrict__ cursor, float* __restrict__ degf) {
    int i = blockIdx.x * 256 + threadIdx.x;
    if (i < 30000) {
        u32 end = cursor[i];
        u32 beg = (i > 0) ? cursor[i - 1] : 0u;
        degf[i] = (float)(end - beg);
    }
}

// ---- weights -> k-tile-blocked bf16 layout (N=256) ----
__global__ void to_blocked(const void* src, int K, int ktiles, const int* flag,
                           u16* dst) {
    int idx = blockIdx.x * 256 + threadIdx.x;
    int total = ktiles * 4 * 256 * 8;
    if (idx >= total) return;
    int f32 = flag[0];
    int c = idx & 7;
    int n = (idx >> 3) & 255;
    int jk = idx >> 11;
    int j = jk & 3, kt = jk >> 2;
    int k = kt * 32 + j * 8 + c;
    u16 v = 0;
    if (k < K) v = f2bu(ldv(src, k * 256 + n, f32));
    dst[idx] = v;
}

// ---- Wcat = [Wih; Whh] -> blocked layout, N=1024, ktiles=24 ----
__global__ void to_blocked2(const void* src1, int K1, const void* src2, int K2,
                            const int* flag, u16* dst) {
    int idx = blockIdx.x * 256 + threadIdx.x;
    int total = 24 * 4 * 1024 * 8;
    if (idx >= total) return;
    int f32 = flag[0];
    int c = idx & 7;
    int n = (idx >> 3) & 1023;
    int jk = idx >> 13;
    int j = jk & 3, kt = jk >> 2;
    int k = kt * 32 + j * 8 + c;
    u16 v = 0;
    if (k < K1) v = f2bu(ldv(src1, k * 1024 + n, f32));
    else if (k - K1 < K2) v = f2bu(ldv(src2, (k - K1) * 1024 + n, f32));
    dst[idx] = v;
}

// ---- lin0: h0 = relu(x @ W0 + b0), 8 nodes/block, W0 column in registers ----
__global__ __launch_bounds__(256) void lin0_kernel(const void* x, const void* W0,
                                                   const void* b0, const int* flag,
                                                   u16* h0b) {
    int f32 = flag[0];
    int n0 = blockIdx.x * 8, tid = threadIdx.x;
    __shared__ float xs[8][26];
    if (tid < 200) {
        int nn = tid / 25, k = tid % 25;
        xs[nn][k] = ldv(x, (n0 + nn) * 25 + k, f32);
    }
    __syncthreads();
    float wr[25];
    #pragma unroll
    for (int k = 0; k < 25; ++k) wr[k] = ldv(W0, k * 256 + tid, f32);
    float bias = ldv(b0, tid, f32);
    #pragma unroll
    for (int nn = 0; nn < 8; ++nn) {
        float a = bias;
        #pragma unroll
        for (int k = 0; k < 25; ++k) a += xs[nn][k] * wr[k];
        h0b[(n0 + nn) * 256 + tid] = f2bu(fmaxf(a, 0.0f));
    }
}

// ---- Q = h0 @ Wm1top (K=256, first 8 ktiles of Wm1b), bf16 out ----
__global__ __launch_bounds__(256) void qgen_kernel(
    const u16* __restrict__ h0b, const u16* __restrict__ Wm1b,
    u16* __restrict__ Qb) {
    __shared__ __attribute__((aligned(16))) u16 As[64 * 264];
    const int tid = threadIdx.x;
    const int w = tid >> 6, lane = tid & 63, quad = lane >> 4, mrow = lane & 15;
    const int row0 = blockIdx.x * 64;
    const int colb = w * 64 + mrow;
    const int r = tid >> 2, sub = tid & 3;

    {
        int row = row0 + r;
        u16* arow = As + r * 264;
        #pragma unroll
        for (int j = 0; j < 8; ++j) {
            int c0 = sub * 64 + j * 8;
            s16x8 v = {0, 0, 0, 0, 0, 0, 0, 0};
            if (row < 30000) v = *(const s16x8*)(h0b + row * 256 + c0);
            *(s16x8*)(arow + c0) = v;
        }
    }
    __syncthreads();

    f32x4 acc[4][4];
    f32x4 fzero = {0.f, 0.f, 0.f, 0.f};
    #pragma unroll
    for (int mi = 0; mi < 4; ++mi)
        #pragma unroll
        for (int ni = 0; ni < 4; ++ni) acc[mi][ni] = fzero;

    for (int kt = 0; kt < 8; ++kt) {
        s16x8 af[4], bf[4];
        #pragma unroll
        for (int ni = 0; ni < 4; ++ni)
            bf[ni] = *(const s16x8*)(Wm1b + (((kt * 4 + quad) * 256) + colb + ni * 16) * 8);
        #pragma unroll
        for (int mi = 0; mi < 4; ++mi)
            af[mi] = *(const s16x8*)(As + (mi * 16 + mrow) * 264 + kt * 32 + quad * 8);
        #pragma unroll
        for (int mi = 0; mi < 4; ++mi)
            #pragma unroll
            for (int ni = 0; ni < 4; ++ni)
                acc[mi][ni] = __builtin_amdgcn_mfma_f32_16x16x32_bf16(af[mi], bf[ni], acc[mi][ni], 0, 0, 0);
    }

    #pragma unroll
    for (int mi = 0; mi < 4; ++mi)
        #pragma unroll
        for (int rg = 0; rg < 4; ++rg) {
            int row = row0 + mi * 16 + quad * 4 + rg;
            if (row >= 30000) continue;
            #pragma unroll
            for (int ni = 0; ni < 4; ++ni)
                Qb[row * 256 + colb + ni * 16] = f2bu(acc[mi][ni][rg]);
        }
}

// ---- fast-path edge aggregation: uniform 64-edge blocks, ~6 KB LDS.
// eattr@Wm1_bot via one K=32 MFMA tile per wave; Q[src] added via scalar gather;
// register-resident segmented reduction over the dst-sorted 64-edge tile
// (segment ids via ballot/popcount, predicated per-lane partials, cross-quad
// shfl_xor combine, one atomicAdd per segment per column). ----
__global__ __launch_bounds__(256) void edge_qscan_kernel(
    const u16* __restrict__ Qb, const void* __restrict__ eattr,
    const int* __restrict__ eidx,
    const u16* __restrict__ permLo, const u8* __restrict__ permHi,
    const u16* __restrict__ Wm1b, const void* __restrict__ bm1,
    const int* __restrict__ flag, float* __restrict__ aggP) {
    __shared__ __attribute__((aligned(16))) u16 Ae[64 * 40];   // 64 edges x K32 (stride 40)
    __shared__ int eids[64];
    __shared__ int srcs[64];
    __shared__ int dsh[64];
    __shared__ u8 segid_s[64];
    __shared__ int segdst[64];
    __shared__ int nseg_s;
    const int f32 = flag[0];
    const int tid = threadIdx.x;
    const int w = tid >> 6, lane = tid & 63, quad = lane >> 4, mrow = lane & 15;
    const int eb0 = blockIdx.x * 64;
    const int colb = w * 64 + mrow;

    if (tid < 64) {
        int si = eb0 + tid;
        int e = (int)permLo[si] | ((int)permHi[si] << 16);
        eids[tid] = e;
        srcs[tid] = eidx[e];
        dsh[tid] = eidx[480000 + e];
    }
    __syncthreads();

    // wave 0: segment ids + per-segment dst via ballot.
    // BUGFIX (round-5 crash): segment id = popcount(flags at positions <= tid) - 1.
    // The old "strictly below" form gave unflagged lanes id+1 and, when lane 63
    // was unflagged, overcounted nseg -> read of uninitialized segdst[] -> OOB
    // atomicAdd -> memory fault.
    if (tid < 64) {
        int d = dsh[tid];
        int fl = (tid == 0) || (d != dsh[tid - 1]);
        unsigned long long mask = __ballot(fl);
        int sid = (int)__popcll(mask & ((2ull << tid) - 1ull)) - 1;
        segid_s[tid] = (u8)sid;
        if (fl) segdst[sid] = d;
        if (tid == 63) nseg_s = sid + 1;
    }
    // all threads: stage eattr rows (bf16, zero-padded to K=32)
    for (int idx = tid; idx < 64 * 32; idx += 256) {
        int row = idx >> 5, c = idx & 31;
        u16 v = 0;
        if (c < 14) v = f2bu(ldv(eattr, eids[row] * 14 + c, f32));
        Ae[row * 40 + c] = v;
    }

    // hoisted block-invariant B fragments (kt=8 slice of Wm1b) + bias
    s16x8 bf[4];
    float bm1c[4];
    #pragma unroll
    for (int ni = 0; ni < 4; ++ni) {
        bf[ni] = *(const s16x8*)(Wm1b + (((32 + quad) * 256) + colb + ni * 16) * 8);
        bm1c[ni] = ldv(bm1, colb + ni * 16, f32);
    }
    __syncthreads();

    // MFMA: 64 edges x 64 cols per wave, K=32 (eattr block)
    f32x4 acc[4][4];
    const f32x4 fzero = {0.f, 0.f, 0.f, 0.f};
    #pragma unroll
    for (int mi = 0; mi < 4; ++mi) {
        s16x8 af = *(const s16x8*)(Ae + (mi * 16 + mrow) * 40 + quad * 8);
        #pragma unroll
        for (int ni = 0; ni < 4; ++ni)
            acc[mi][ni] = __builtin_amdgcn_mfma_f32_16x16x32_bf16(af, bf[ni], fzero, 0, 0, 0);
    }

    // epilogue: m = relu(acc + bm1 + Q[src]); also pick up per-row segment ids
    int sid_r[4][4];
    #pragma unroll
    for (int mi = 0; mi < 4; ++mi)
        #pragma unroll
        for (int rg = 0; rg < 4; ++rg) {
            int row = mi * 16 + quad * 4 + rg;
            int src = srcs[row];
            sid_r[mi][rg] = segid_s[row];
            const u16* qrow = Qb + src * 256;
            #pragma unroll
            for (int ni = 0; ni < 4; ++ni)
                acc[mi][ni][rg] = fmaxf(acc[mi][ni][rg] + bm1c[ni] + b2f(qrow[colb + ni * 16]), 0.0f);
        }

    // register-resident segmented reduction
    int nseg = nseg_s;
    for (int s = 0; s < nseg; ++s) {
        float ps[4] = {0.f, 0.f, 0.f, 0.f};
        #pragma unroll
        for (int mi = 0; mi < 4; ++mi)
            #pragma unroll
            for (int rg = 0; rg < 4; ++rg) {
                bool in = (sid_r[mi][rg] == s);
                #pragma unroll
                for (int ni = 0; ni < 4; ++ni)
                    ps[ni] += in ? acc[mi][ni][rg] : 0.0f;
            }
        #pragma unroll
        for (int ni = 0; ni < 4; ++ni) {
            float v = ps[ni];
            v += __shfl_xor(v, 16, 64);
            v += __shfl_xor(v, 32, 64);
            ps[ni] = v;
        }
        if (quad == 0) {
            int d = segdst[s];
            #pragma unroll
            for (int ni = 0; ni < 4; ++ni)
                atomicAdd(&aggP[d * 256 + colb + ni * 16], ps[ni]);
        }
    }
}

// ---- FALLBACK edge kernel (round-10, proven): GEMM1 in-kernel, atomic aggP ----
__global__ __launch_bounds__(256) void edge_sorted_kernel(
    const u16* __restrict__ h0b, const void* __restrict__ eattr,
    const int* __restrict__ eidx,
    const u16* __restrict__ permLo, const u8* __restrict__ permHi,
    const u16* __restrict__ Wm1b,
    const void* __restrict__ bm1,
    const int* __restrict__ flag, float* __restrict__ aggP) {
    __shared__ __attribute__((aligned(16))) u16 As[64 * 296];
    __shared__ int dsh[64];
    const int f32 = flag[0];
    const int tid = threadIdx.x;
    const int w = tid >> 6, lane = tid & 63, quad = lane >> 4, mrow = lane & 15;
    const int eb0 = blockIdx.x * 64;
    const int colb = w * 64 + mrow;

    if (tid < 64) {
        int sj = eb0 + tid;
        int ee = (int)permLo[sj] | ((int)permHi[sj] << 16);
        dsh[tid] = eidx[480000 + ee];
    }
    {
        int r = tid >> 2, sub = tid & 3;
        int si = eb0 + r;
        int e = (int)permLo[si] | ((int)permHi[si] << 16);
        int src = eidx[e];
        const u16* hrow = h0b + src * 256;
        u16* arow = As + r * 296;
        #pragma unroll
        for (int j = 0; j < 8; ++j) {
            int c0 = sub * 64 + j * 8;
            *(s16x8*)(arow + c0) = *(const s16x8*)(hrow + c0);
        }
        if (sub == 0) {
            for (int c = 0; c < 14; ++c) arow[256 + c] = f2bu(ldv(eattr, e * 14 + c, f32));
            for (int c = 14; c < 40; ++c) arow[256 + c] = 0;
        }
    }
    __syncthreads();

    f32x4 acc[4][4];
    f32x4 fzero = {0.f, 0.f, 0.f, 0.f};
    #pragma unroll
    for (int mi = 0; mi < 4; ++mi)
        #pragma unroll
        for (int ni = 0; ni < 4; ++ni) acc[mi][ni] = fzero;

    for (int kt = 0; kt < 9; ++kt) {
        s16x8 af[4], bf[4];
        #pragma unroll
        for (int ni = 0; ni < 4; ++ni)
            bf[ni] = *(const s16x8*)(Wm1b + (((kt * 4 + quad) * 256) + colb + ni * 16) * 8);
        #pragma unroll
        for (int mi = 0; mi < 4; ++mi)
            af[mi] = *(const s16x8*)(As + (mi * 16 + mrow) * 296 + kt * 32 + quad * 8);
        #pragma unroll
        for (int mi = 0; mi < 4; ++mi)
            #pragma unroll
            for (int ni = 0; ni < 4; ++ni)
                acc[mi][ni] = __builtin_amdgcn_mfma_f32_16x16x32_bf16(af[mi], bf[ni], acc[mi][ni], 0, 0, 0);
    }

    float bm1c[4];
    #pragma unroll
    for (int ni = 0; ni < 4; ++ni) bm1c[ni] = ldv(bm1, colb + ni * 16, f32);
    __syncthreads();
    #pragma unroll
    for (int mi = 0; mi < 4; ++mi)
        #pragma unroll
        for (int ni = 0; ni < 4; ++ni)
            #pragma unroll
            for (int rg = 0; rg < 4; ++rg) {
                int row = mi * 16 + quad * 4 + rg;
                As[row * 296 + colb + ni * 16] = f2bu(fmaxf(acc[mi][ni][rg] + bm1c[ni], 0.0f));
            }
    __syncthreads();

    {
        int c = tid;
        float s = 0.0f;
        int cur = dsh[0];
        #pragma unroll 8
        for (int rr = 0; rr < 64; ++rr) {
            int d = dsh[rr];
            if (d != cur) { atomicAdd(&aggP[cur * 256 + c], s); s = 0.0f; cur = d; }
            s += b2f(As[rr * 296 + c]);
        }
        atomicAdd(&aggP[cur * 256 + c], s);
    }
}

// ---- fused node update: out = relu(h0@Wr + aggP@Wm2 + br + deg*bm2), in-place bf16 ----
__global__ __launch_bounds__(256) void node_dual_kernel(
    u16* __restrict__ h0b, const u16* __restrict__ Wrb, const u16* __restrict__ Wm2b,
    const void* __restrict__ br, const void* __restrict__ bm2,
    const float* __restrict__ aggP, const float* __restrict__ degf,
    const int* __restrict__ flag) {
    __shared__ __attribute__((aligned(16))) u16 As[64 * 264];
    const int f32 = flag[0];
    const int tid = threadIdx.x;
    const int w = tid >> 6, lane = tid & 63, quad = lane >> 4, mrow = lane & 15;
    const int row0 = blockIdx.x * 64;
    const int colb = w * 64 + mrow;
    const int r = tid >> 2, sub = tid & 3;

    {
        int row = row0 + r;
        u16* arow = As + r * 264;
        #pragma unroll
        for (int j = 0; j < 8; ++j) {
            int c0 = sub * 64 + j * 8;
            s16x8 v = {0, 0, 0, 0, 0, 0, 0, 0};
            if (row < 30000) v = *(const s16x8*)(h0b + row * 256 + c0);
            *(s16x8*)(arow + c0) = v;
        }
    }
    __syncthreads();

    f32x4 acc[4][4];
    f32x4 fzero = {0.f, 0.f, 0.f, 0.f};
    #pragma unroll
    for (int mi = 0; mi < 4; ++mi)
        #pragma unroll
        for (int ni = 0; ni < 4; ++ni) acc[mi][ni] = fzero;

    for (int kt = 0; kt < 8; ++kt) {
        s16x8 af[4], bf[4];
        #pragma unroll
        for (int ni = 0; ni < 4; ++ni)
            bf[ni] = *(const s16x8*)(Wrb + (((kt * 4 + quad) * 256) + colb + ni * 16) * 8);
        #pragma unroll
        for (int mi = 0; mi < 4; ++mi)
            af[mi] = *(const s16x8*)(As + (mi * 16 + mrow) * 264 + kt * 32 + quad * 8);
        #pragma unroll
        for (int mi = 0; mi < 4; ++mi)
            #pragma unroll
            for (int ni = 0; ni < 4; ++ni)
                acc[mi][ni] = __builtin_amdgcn_mfma_f32_16x16x32_bf16(af[mi], bf[ni], acc[mi][ni], 0, 0, 0);
    }
    __syncthreads();

    // restage aggP rows (f32 -> bf16), vectorized
    {
        int row = row0 + r;
        u16* arow = As + r * 264;
        #pragma unroll
        for (int j = 0; j < 8; ++j) {
            int c0 = sub * 64 + j * 8;
            s16x8 pk = {0, 0, 0, 0, 0, 0, 0, 0};
            if (row < 30000) {
                f32x4 a = *(const f32x4*)(aggP + row * 256 + c0);
                f32x4 b = *(const f32x4*)(aggP + row * 256 + c0 + 4);
                pk[0] = (short)f2bu(a[0]); pk[1] = (short)f2bu(a[1]);
                pk[2] = (short)f2bu(a[2]); pk[3] = (short)f2bu(a[3]);
                pk[4] = (short)f2bu(b[0]); pk[5] = (short)f2bu(b[1]);
                pk[6] = (short)f2bu(b[2]); pk[7] = (short)f2bu(b[3]);
            }
            *(s16x8*)(arow + c0) = pk;
        }
    }
    __syncthreads();

    for (int kt = 0; kt < 8; ++kt) {
        s16x8 af[4], bf[4];
        #pragma unroll
        for (int ni = 0; ni < 4; ++ni)
            bf[ni] = *(const s16x8*)(Wm2b + (((kt * 4 + quad) * 256) + colb + ni * 16) * 8);
        #pragma unroll
        for (int mi = 0; mi < 4; ++mi)
            af[mi] = *(const s16x8*)(As + (mi * 16 + mrow) * 264 + kt * 32 + quad * 8);
        #pragma unroll
        for (int mi = 0; mi < 4; ++mi)
            #pragma unroll
            for (int ni = 0; ni < 4; ++ni)
                acc[mi][ni] = __builtin_amdgcn_mfma_f32_16x16x32_bf16(af[mi], bf[ni], acc[mi][ni], 0, 0, 0);
    }

    #pragma unroll
    for (int mi = 0; mi < 4; ++mi)
        #pragma unroll
        for (int rg = 0; rg < 4; ++rg) {
            int row = row0 + mi * 16 + quad * 4 + rg;
            if (row >= 30000) continue;
            float dg = degf[row];
            #pragma unroll
            for (int ni = 0; ni < 4; ++ni) {
                int col = colb + ni * 16;
                float v = acc[mi][ni][rg] + ldv(br, col, f32) + dg * ldv(bm2, col, f32);
                h0b[row * 256 + col] = f2bu(fmaxf(v, 0.0f));
            }
        }
}

// ---- Set2Set gates via MFMA: 128 blocks (64x64 tiles, wave = 16 cols) ----
__global__ __launch_bounds__(256) void gates_mfma_kernel(
    const u16* __restrict__ Abuf, const u16* __restrict__ Wcatb,
    float* __restrict__ G) {
    const int tid = threadIdx.x;
    const int w = tid >> 6, lane = tid & 63, quad = lane >> 4, mrow = lane & 15;
    const int row0 = blockIdx.x * 64;
    const int col = blockIdx.y * 64 + w * 16 + mrow;

    f32x4 acc[4];
    f32x4 fzero = {0.f, 0.f, 0.f, 0.f};
    #pragma unroll
    for (int mi = 0; mi < 4; ++mi) acc[mi] = fzero;

    for (int kt = 0; kt < 24; ++kt) {
        s16x8 bfv = *(const s16x8*)(Wcatb + (((kt * 4 + quad) * 1024) + col) * 8);
        s16x8 af[4];
        #pragma unroll
        for (int mi = 0; mi < 4; ++mi)
            af[mi] = *(const s16x8*)(Abuf + (row0 + mi * 16 + mrow) * 768 + kt * 32 + quad * 8);
        #pragma unroll
        for (int mi = 0; mi < 4; ++mi)
            acc[mi] = __builtin_amdgcn_mfma_f32_16x16x32_bf16(af[mi], bfv, acc[mi], 0, 0, 0);
    }

    #pragma unroll
    for (int mi = 0; mi < 4; ++mi)
        #pragma unroll
        for (int rg = 0; rg < 4; ++rg)
            G[(row0 + mi * 16 + quad * 4 + rg) * 1024 + col] = acc[mi][rg];
}

// ---- LSTM elementwise ----
__global__ __launch_bounds__(256) void lstm_kernel(const float* G, const void* bl,
                                                   const int* flag,
                                                   float* Cst, float* Hst,
                                                   u16* Abuf) {
    int f32 = flag[0];
    int b = blockIdx.x, d = threadIdx.x;
    float gi = G[b * 1024 + d]       + ldv(bl, d, f32);
    float gf = G[b * 1024 + 256 + d] + ldv(bl, 256 + d, f32);
    float gg = G[b * 1024 + 512 + d] + ldv(bl, 512 + d, f32);
    float go = G[b * 1024 + 768 + d] + ldv(bl, 768 + d, f32);
    float c = Cst[b * 256 + d];
    c = sigm(gf) * c + sigm(gi) * tanhf(gg);
    Cst[b * 256 + d] = c;
    float h = sigm(go) * tanhf(c);
    Hst[b * 256 + d] = h;
    u16 hb = f2bu(h);
    Abuf[b * 768 + d] = hb;
    Abuf[b * 768 + 512 + d] = hb;
}

// ---- fused Set2Set attention: e = out.h[batch], segment softmax, r = sum a*out.
// One block per graph; graph's node rows are CONTIGUOUS (batch sorted) -> stage
// them once in LDS (<=112 rows, 59.8 KB LDS total), compute e wave-parallel,
// softmax + weighted sum entirely from LDS. Fallback (cnt>112) from global. ----
#define GROWS 112
__global__ __launch_bounds__(256) void s2s_fused_kernel(
    const u16* __restrict__ outb, const float* __restrict__ Hst,
    const int* __restrict__ batch, float* __restrict__ Rst,
    u16* __restrict__ Abuf, float* __restrict__ ebuf) {
    __shared__ __attribute__((aligned(16))) u16 Ls[GROWS * 256];
    __shared__ __attribute__((aligned(16))) float hsh[256];
    __shared__ float esh[GROWS];
    __shared__ float red[256];
    const int b = blockIdx.x, tid = threadIdx.x;
    const int w = tid >> 6, lane = tid & 63;
    const int n0 = lower_bound(batch, 30000, b);
    const int n1 = lower_bound(batch, 30000, b + 1);
    const int cnt = n1 - n0;
    hsh[tid] = Hst[b * 256 + tid];
    __syncthreads();
    float r_out = 0.0f;
    if (cnt > 0 && cnt <= GROWS) {
        // stage graph rows (contiguous, coalesced)
        for (int idx = tid; idx < cnt * 32; idx += 256) {
            int i = idx >> 5, c8 = idx & 31;
            *(s16x8*)(Ls + i * 256 + c8 * 8) = *(const s16x8*)(outb + (n0 + i) * 256 + c8 * 8);
        }
        __syncthreads();
        // e per node: wave w handles nodes w, w+4, ...
        for (int i = w; i < cnt; i += 4) {
            s16x4 ov = *(const s16x4*)(Ls + i * 256 + lane * 4);
            f32x4 hv = *(const f32x4*)(hsh + lane * 4);
            float p = b2f((u16)ov[0]) * hv[0] + b2f((u16)ov[1]) * hv[1]
                    + b2f((u16)ov[2]) * hv[2] + b2f((u16)ov[3]) * hv[3];
            #pragma unroll
            for (int off = 1; off < 64; off <<= 1) p += __shfl_xor(p, off, 64);
            if (lane == 0) esh[i] = p;
        }
        __syncthreads();
        // softmax over esh[0..cnt)
        float m = -1e30f;
        for (int i = tid; i < cnt; i += 256) m = fmaxf(m, esh[i]);
        red[tid] = m; __syncthreads();
        for (int s = 128; s > 0; s >>= 1) { if (tid < s) red[tid] = fmaxf(red[tid], red[tid + s]); __syncthreads(); }
        m = red[0]; __syncthreads();
        float sl = 0.0f;
        for (int i = tid; i < cnt; i += 256) { float pe = expf(esh[i] - m); esh[i] = pe; sl += pe; }
        red[tid] = sl; __syncthreads();
        for (int s = 128; s > 0; s >>= 1) { if (tid < s) red[tid] += red[tid + s]; __syncthreads(); }
        float ssum = red[0]; __syncthreads();
        // weighted feature sum from LDS
        float acc = 0.0f;
        for (int i = 0; i < cnt; ++i) acc += esh[i] * b2f(Ls[i * 256 + tid]);
        r_out = acc / ssum;
    } else if (cnt > GROWS) {
        // fallback: compute e to global ebuf, then two-pass softmax from global
        for (int i = w; i < cnt; i += 4) {
            const u16* orow = outb + (n0 + i) * 256 + lane * 4;
            f32x4 hv = *(const f32x4*)(hsh + lane * 4);
            float p = b2f(orow[0]) * hv[0] + b2f(orow[1]) * hv[1]
                    + b2f(orow[2]) * hv[2] + b2f(orow[3]) * hv[3];
            #pragma unroll
            for (int off = 1; off < 64; off <<= 1) p += __shfl_xor(p, off, 64);
            if (lane == 0) ebuf[n0 + i] = p;
        }
        __syncthreads();
        float m = -1e30f;
        for (int n = n0 + tid; n < n1; n += 256) m = fmaxf(m, ebuf[n]);
        red[tid] = m; __syncthreads();
        for (int s = 128; s > 0; s >>= 1) { if (tid < s) red[tid] = fmaxf(red[tid], red[tid + s]); __syncthreads(); }
        m = red[0]; __syncthreads();
        float sl = 0.0f;
        for (int n = n0 + tid; n < n1; n += 256) sl += expf(ebuf[n] - m);
        red[tid] = sl; __syncthreads();
        for (int s = 128; s > 0; s >>= 1) { if (tid < s) red[tid] += red[tid + s]; __syncthreads(); }
        float ssum = red[0]; __syncthreads();
        float acc = 0.0f;
        for (int c0 = n0; c0 < n1; c0 += 256) {
            int nn = n1 - c0; if (nn > 256) nn = 256;
            __syncthreads();
            if (tid < nn) red[tid] = expf(ebuf[c0 + tid] - m);
            __syncthreads();
            for (int i = 0; i < nn; ++i) acc += red[i] * b2f(outb[(c0 + i) * 256 + tid]);
        }
        r_out = acc / ssum;
    }
    Rst[b * 256 + tid] = r_out;
    Abuf[b * 768 + 256 + tid] = f2bu(r_out);
}

// ---- readout + stage diagnostics ----
__global__ __launch_bounds__(256) void readout_kernel(const float* Hst, const float* Rst,
                                                      const void* W1, const void* b1,
                                                      const void* W2, const void* b2,
                                                      const u16* nodeout, const float* aggP,
                                                      const int* flag, void* out) {
    int f32 = flag[0];
    int b = blockIdx.x, tid = threadIdx.x;
    __shared__ float qs[512];
    __shared__ float red[256];
    qs[tid] = Hst[b * 256 + tid];
    qs[256 + tid] = Rst[b * 256 + tid];
    __syncthreads();
    float a = ldv(b1, tid, f32);
    for (int k = 0; k < 512; ++k) a += qs[k] * ldv(W1, k * 256 + tid, f32);
    a = fmaxf(a, 0.0f) * ldv(W2, tid, f32);
    red[tid] = a; __syncthreads();
    for (int s = 128; s > 0; s >>= 1) { if (tid < s) red[tid] += red[tid + s]; __syncthreads(); }
    if (tid == 0) {
        float D = 0.0f;
        if (b == 0) {
            float s1 = 0.0f, s2 = 0.0f, s3 = 0.0f;
            for (int i = 0; i < 256; ++i) {
                s1 += fabsf(b2f(nodeout[i]));
                s2 += fabsf(aggP[i]);
                s3 += fabsf(Rst[i]);
            }
            if (s1 < 1e-3f) D += 100.0f;
            if (s2 < 1e-3f) D += 200.0f;
            if (s3 < 1e-6f) D += 400.0f;
        }
        stv(out, b, red[0] + ldv(b2, 0, f32) + D, f32);
    }
}

// ---------------- workspace layout (bytes) ----------------
#define OFF_FLAG 0
#define OFF_HST  64
#define OFF_RST  524352
#define OFF_CST  1048640
#define OFF_PLO  64
#define OFF_PHI  960064
#define OFF_CUR  1440064
#define OFF_WREG 1572928
#define OFF_WM1B (OFF_WREG)
#define OFF_WM2B (OFF_WREG + 147456)
#define OFF_WRB  (OFF_WREG + 278528)
#define OFF_WCAT (OFF_WREG + 409600)
#define OFF_E    3670080
#define OFF_AGG  3790144
#define OFF_ABUF (OFF_AGG + 1048576)
#define OFF_G    (OFF_AGG + 4194304)
#define OFF_H0B  34510144
#define WS_NEEDED 49870144
#define OFF_Q    49870144                 // fast path only: Q bf16 [30000x256]
#define WS_FAST  (49870144 + 15360000)

extern "C" __attribute__((visibility("default")))
void kernel_launch(void* const* d_in, const int* in_sizes, int n_in,
                   void* d_out, int out_size, void* d_ws, size_t ws_size,
                   hipStream_t stream) {
    char* ws = (char*)d_ws;
    int*   flag   = (int*)(ws + OFF_FLAG);
    float* Hst    = (float*)(ws + OFF_HST);
    float* Rst    = (float*)(ws + OFF_RST);
    float* Cst    = (float*)(ws + OFF_CST);
    u16*   permLo = (u16*)(ws + OFF_PLO);
    u8*    permHi = (u8*)(ws + OFF_PHI);
    u32*   cursor = (u32*)(ws + OFF_CUR);
    u16*   Wm1b   = (u16*)(ws + OFF_WM1B);
    u16*   Wm2b   = (u16*)(ws + OFF_WM2B);
    u16*   Wrb    = (u16*)(ws + OFF_WRB);
    u16*   Wcatb  = (u16*)(ws + OFF_WCAT);
    float* ebuf   = (float*)(ws + OFF_E);
    u32*   part   = (u32*)(ws + OFF_E);
    u32*   pexcl  = (u32*)(ws + OFF_E + 512);
    float* degf   = (float*)(ws + OFF_E);
    float* aggP   = (float*)(ws + OFF_AGG);
    u16*   Abuf   = (u16*)(ws + OFF_ABUF);
    float* G      = (float*)(ws + OFF_G);
    u16*   h0b    = (u16*)(ws + OFF_H0B);
    u16*   Qb     = (u16*)(ws + OFF_Q);

    detect_kernel<<<1, 256, 0, stream>>>(d_in[0], flag);

    bool sizes_ok = (n_in == 19)
        && in_sizes[0] == 30000 * 25
        && in_sizes[1] == 480000 * 14
        && in_sizes[4] == 270 * 256
        && in_sizes[10] == 512 * 1024
        && in_sizes[17] == 2 * 480000
        && in_sizes[18] == 30000;
    if (!sizes_ok) { fillv_kernel<<<2, 256, 0, stream>>>(d_out, flag, 1600.0f); return; }
    if (ws_size < (size_t)WS_NEEDED) { fillv_kernel<<<2, 256, 0, stream>>>(d_out, flag, 800.0f); return; }
    const bool fast = (ws_size >= (size_t)WS_FAST);

    fillv_kernel<<<2, 256, 0, stream>>>(d_out, flag, 3.0f);
    DMPNN_Change_678604832935_kernel<<<1, 64, 0, stream>>>((int*)(ws + OFF_G));

    const void* x     = d_in[0];
    const void* eattr = d_in[1];
    const void* W0    = d_in[2];
    const void* b0    = d_in[3];
    const void* Wm1   = d_in[4];
    const void* bm1   = d_in[5];
    const void* Wm2   = d_in[6];
    const void* bm2   = d_in[7];
    const void* Wr    = d_in[8];
    const void* br    = d_in[9];
    const void* Wih   = d_in[10];
    const void* Whh   = d_in[11];
    const void* bl    = d_in[12];
    const void* W1    = d_in[13];
    const void* b1    = d_in[14];
    const void* W2    = d_in[15];
    const void* b2    = d_in[16];
    const int* eidx   = (const int*)d_in[17];
    const int* batch  = (const int*)d_in[18];

    to_blocked<<<288, 256, 0, stream>>>(Wm1, 270, 9, flag, Wm1b);
    to_blocked<<<256, 256, 0, stream>>>(Wm2, 256, 8, flag, Wm2b);
    to_blocked<<<256, 256, 0, stream>>>(Wr, 256, 8, flag, Wrb);
    to_blocked2<<<3072, 256, 0, stream>>>(Wih, 512, Whh, 256, flag, Wcatb);

    lin0_kernel<<<3750, 256, 0, stream>>>(x, W0, b0, flag, h0b);

    // counting sort of edges by dst (CSR); integer atomics only
    zero_kernel<<<30, 256, 0, stream>>>((float*)cursor, 30000);
    hist_kernel<<<1875, 256, 0, stream>>>(eidx, cursor);
    scan1_kernel<<<118, 256, 0, stream>>>(cursor, part);
    scan2_kernel<<<1, 128, 0, stream>>>(part, pexcl, 118);
    scan3_kernel<<<118, 256, 0, stream>>>(cursor, pexcl);
    scatter_kernel<<<1875, 256, 0, stream>>>(eidx, cursor, permLo, permHi);
    deg_kernel<<<118, 256, 0, stream>>>(cursor, degf);

    zero_kernel<<<1024, 256, 0, stream>>>(aggP, 7680000);
    if (fast) {
        // MFMA fast path: Q per node once, then uniform 64-edge blocks
        qgen_kernel<<<469, 256, 0, stream>>>(h0b, Wm1b, Qb);
        edge_qscan_kernel<<<7500, 256, 0, stream>>>(Qb, eattr, eidx, permLo, permHi,
                                                    Wm1b, bm1, flag, aggP);
    } else {
        edge_sorted_kernel<<<7500, 256, 0, stream>>>(h0b, eattr, eidx, permLo, permHi,
                                                     Wm1b, bm1, flag, aggP);
    }
    node_dual_kernel<<<469, 256, 0, stream>>>(h0b, Wrb, Wm2b, br, bm2, aggP, degf, flag);

    zero_kernel<<<64, 256, 0, stream>>>(Cst, 131072);
    zero_kernel<<<64, 256, 0, stream>>>((float*)Abuf, 196608);

    for (int s = 0; s < 3; ++s) {
        gates_mfma_kernel<<<dim3(8, 16), 256, 0, stream>>>(Abuf, Wcatb, G);
        lstm_kernel<<<512, 256, 0, stream>>>(G, bl, flag, Cst, Hst, Abuf);
        s2s_fused_kernel<<<512, 256, 0, stream>>>(h0b, Hst, batch, Rst, Abuf, ebuf);
    }
    readout_kernel<<<512, 256, 0, stream>>>(Hst, Rst, W1, b1, W2, b2, h0b, aggP, flag, d_out);
}

// Round 8
// 489.033 us; speedup vs baseline: 1.1032x; 1.1032x over previous
//
#include <hip/hip_runtime.h>

typedef unsigned short u16;
typedef unsigned char u8;
typedef unsigned int u32;
using s16x8 = __attribute__((ext_vector_type(8))) short;
using s16x4 = __attribute__((ext_vector_type(4))) short;
using f32x4 = __attribute__((ext_vector_type(4))) float;

#define DEV static __device__ __forceinline__

DEV float b2f(u16 u) { return __uint_as_float(((u32)u) << 16); }
DEV u16 f2bu(float f) {               // f32 -> bf16 bits, round-to-nearest-even
    u32 u = __float_as_uint(f);
    u32 r = (u + 0x7FFFu + ((u >> 16) & 1u)) >> 16;
    return (u16)r;
}
DEV float sigm(float x) { return 1.0f / (1.0f + expf(-x)); }

DEV float ldv(const void* p, int i, int f32flag) {
    if (f32flag) return ((const float*)p)[i];
    return b2f(((const u16*)p)[i]);
}
DEV void stv(void* p, int i, float v, int f32flag) {
    if (f32flag) ((float*)p)[i] = v;
    else ((u16*)p)[i] = f2bu(v);
}

DEV int lower_bound(const int* b, int n, int v) {
    int lo = 0, hi = n;
    while (lo < hi) { int mid = (lo + hi) >> 1; if (b[mid] < v) lo = mid + 1; else hi = mid; }
    return lo;
}

// identifier-named kernel from the stub skeleton (kept; harmless)
__global__ void DMPNN_Change_678604832935_kernel(int* p) {
    if (p && threadIdx.x == 0 && blockIdx.x == 0) p[0] = 1;
}

// ---- dtype sniffer ----
__global__ void detect_kernel(const void* x, int* flag) {
    __shared__ int cnt[128];
    int tid = threadIdx.x;
    if (tid < 128) {
        u16 v = ((const u16*)x)[tid];
        int e = (v >> 7) & 0xFF;
        cnt[tid] = (e >= 100 && e <= 141) ? 1 : 0;
    }
    __syncthreads();
    if (tid == 0) {
        int s = 0;
        for (int i = 0; i < 128; ++i) s += cnt[i];
        flag[0] = (s < 110) ? 1 : 0;   // 1 = float32 data, 0 = bf16 data
    }
}

__global__ void fillv_kernel(void* out, const int* flag, float v) {
    int i = blockIdx.x * 256 + threadIdx.x;
    if (i < 512) stv(out, i, v, flag[0]);
}

__global__ void zero_kernel(float* p, int n) {
    int i = blockIdx.x * 256 + threadIdx.x;
    int stride = gridDim.x * 256;
    for (; i < n; i += stride) p[i] = 0.0f;
}

// one launch zeroing two regions (Cst, Abuf) — runs AFTER node_dual because
// Abuf aliases the aggP region (workspace reuse); see layout invariant below.
__global__ void zero2_kernel(float* a, int na, float* b, int nb) {
    int i = blockIdx.x * 256 + threadIdx.x;
    int stride = gridDim.x * 256;
    for (int j = i; j < na; j += stride) a[j] = 0.0f;
    for (int j = i; j < nb; j += stride) b[j] = 0.0f;
}

// ---- counting sort of edges by dst: histogram -> scan -> scatter ----
// (integer atomics only: counts/positions are order-invariant; the permutation
//  order within a segment is canonicalized later by the rank sort)
__global__ void hist_kernel(const int* __restrict__ eidx, u32* __restrict__ cnt) {
    int i = blockIdx.x * 256 + threadIdx.x;
    if (i < 480000) atomicAdd(&cnt[eidx[480000 + i]], 1u);
}

__global__ void scan1_kernel(const u32* __restrict__ cnt, u32* __restrict__ part) {
    __shared__ u32 s[256];
    int i = blockIdx.x * 256 + threadIdx.x;
    s[threadIdx.x] = (i < 30000) ? cnt[i] : 0u;
    __syncthreads();
    for (int st = 128; st > 0; st >>= 1) {
        if (threadIdx.x < st) s[threadIdx.x] += s[threadIdx.x + st];
        __syncthreads();
    }
    if (threadIdx.x == 0) part[blockIdx.x] = s[0];
}

// wave-parallel exclusive scan of <=128 partials (was a 1-thread serial loop)
__global__ void scan2_kernel(const u32* __restrict__ part, u32* __restrict__ pexcl, int nb) {
    int tid = threadIdx.x;              // blockDim = 128
    u32 v = (tid < nb) ? part[tid] : 0u;
    u32 x = v;
    #pragma unroll
    for (int off = 1; off < 64; off <<= 1) {
        u32 t = __shfl_up(x, off, 64);
        if ((tid & 63) >= off) x += t;
    }
    __shared__ u32 wsum;
    if (tid == 63) wsum = x;
    __syncthreads();
    u32 add = (tid >= 64) ? wsum : 0u;
    if (tid < nb) pexcl[tid] = x + add - v;   // exclusive
}

__global__ void scan3_kernel(u32* __restrict__ cursor, const u32* __restrict__ pexcl) {
    __shared__ u32 s[256];
    int b = blockIdx.x, tid = threadIdx.x;
    int i = b * 256 + tid;
    u32 v = (i < 30000) ? cursor[i] : 0u;
    s[tid] = v;
    __syncthreads();
    for (int off = 1; off < 256; off <<= 1) {
        u32 t = (tid >= off) ? s[tid - off] : 0u;
        __syncthreads();
        s[tid] += t;
        __syncthreads();
    }
    u32 excl = s[tid] - v + pexcl[b];
    if (i < 30000) cursor[i] = excl;
}

__global__ void scatter_kernel(const int* __restrict__ eidx, u32* __restrict__ cursor,
                               u16* __restrict__ permLo, u8* __restrict__ permHi) {
    int i = blockIdx.x * 256 + threadIdx.x;
    if (i < 480000) {
        int d = eidx[480000 + i];
        u32 pos = atomicAdd(&cursor[d], 1u);
        permLo[pos] = (u16)(i & 0xFFFF);
        permHi[pos] = (u8)(i >> 16);
    }
}

// after scatter, cursor[d] = inclusive end index of segment d -> deg
__global__ void deg_kernel(const u32* __restrict__ cursor, float* __restrict__ degf) {
    int i = blockIdx.x * 256 + threadIdx.x;
    if (i < 30000) {
        u32 end = cursor[i];
        u32 beg = (i > 0) ? cursor[i - 1] : 0u;
        degf[i] = (float)(end - beg);
    }
}

// ---- ALL weights -> k-tile-blocked bf16 layouts in ONE launch ----
// regions: Wm1 (ktiles=9,N=256) | Wm2 (8,256) | Wr (8,256) | Wcat (24,N=1024)
__global__ void to_blocked_all(const void* Wm1, const void* Wm2, const void* Wr,
                               const void* Wih, const void* Whh, const int* flag,
                               u16* Wm1b, u16* Wm2b, u16* Wrb, u16* Wcatb) {
    const int T1 = 9 * 4 * 256 * 8;            // 73728
    const int T2 = T1 + 8 * 4 * 256 * 8;       // +65536
    const int T3 = T2 + 8 * 4 * 256 * 8;       // +65536
    const int T4 = T3 + 24 * 4 * 1024 * 8;     // +786432
    int idx = blockIdx.x * 256 + threadIdx.x;
    if (idx >= T4) return;
    int f32 = flag[0];
    if (idx < T3) {
        const void* src; u16* dst; int K; int l;
        if (idx < T1)      { src = Wm1; dst = Wm1b; K = 270; l = idx; }
        else if (idx < T2) { src = Wm2; dst = Wm2b; K = 256; l = idx - T1; }
        else               { src = Wr;  dst = Wrb;  K = 256; l = idx - T2; }
        int c = l & 7;
        int n = (l >> 3) & 255;
        int jk = l >> 11;
        int j = jk & 3, kt = jk >> 2;
        int k = kt * 32 + j * 8 + c;
        u16 v = 0;
        if (k < K) v = f2bu(ldv(src, k * 256 + n, f32));
        dst[l] = v;
    } else {
        int l = idx - T3;
        int c = l & 7;
        int n = (l >> 3) & 1023;
        int jk = l >> 13;
        int j = jk & 3, kt = jk >> 2;
        int k = kt * 32 + j * 8 + c;
        u16 v = 0;
        if (k < 512) v = f2bu(ldv(Wih, k * 1024 + n, f32));
        else if (k < 768) v = f2bu(ldv(Whh, (k - 512) * 1024 + n, f32));
        Wcatb[l] = v;
    }
}

// ---- lin0: h0 = relu(x @ W0 + b0), 8 nodes/block, W0 column in registers ----
__global__ __launch_bounds__(256) void lin0_kernel(const void* x, const void* W0,
                                                   const void* b0, const int* flag,
                                                   u16* h0b) {
    int f32 = flag[0];
    int n0 = blockIdx.x * 8, tid = threadIdx.x;
    __shared__ float xs[8][26];
    if (tid < 200) {
        int nn = tid / 25, k = tid % 25;
        xs[nn][k] = ldv(x, (n0 + nn) * 25 + k, f32);
    }
    __syncthreads();
    float wr[25];
    #pragma unroll
    for (int k = 0; k < 25; ++k) wr[k] = ldv(W0, k * 256 + tid, f32);
    float bias = ldv(b0, tid, f32);
    #pragma unroll
    for (int nn = 0; nn < 8; ++nn) {
        float a = bias;
        #pragma unroll
        for (int k = 0; k < 25; ++k) a += xs[nn][k] * wr[k];
        h0b[(n0 + nn) * 256 + tid] = f2bu(fmaxf(a, 0.0f));
    }
}

// ---- Q = h0 @ Wm1top (K=256, first 8 ktiles of Wm1b), bf16 out ----
__global__ __launch_bounds__(256) void qgen_kernel(
    const u16* __restrict__ h0b, const u16* __restrict__ Wm1b,
    u16* __restrict__ Qb) {
    __shared__ __attribute__((aligned(16))) u16 As[64 * 264];
    const int tid = threadIdx.x;
    const int w = tid >> 6, lane = tid & 63, quad = lane >> 4, mrow = lane & 15;
    const int row0 = blockIdx.x * 64;
    const int colb = w * 64 + mrow;
    const int r = tid >> 2, sub = tid & 3;

    {
        int row = row0 + r;
        u16* arow = As + r * 264;
        #pragma unroll
        for (int j = 0; j < 8; ++j) {
            int c0 = sub * 64 + j * 8;
            s16x8 v = {0, 0, 0, 0, 0, 0, 0, 0};
            if (row < 30000) v = *(const s16x8*)(h0b + row * 256 + c0);
            *(s16x8*)(arow + c0) = v;
        }
    }
    __syncthreads();

    f32x4 acc[4][4];
    f32x4 fzero = {0.f, 0.f, 0.f, 0.f};
    #pragma unroll
    for (int mi = 0; mi < 4; ++mi)
        #pragma unroll
        for (int ni = 0; ni < 4; ++ni) acc[mi][ni] = fzero;

    for (int kt = 0; kt < 8; ++kt) {
        s16x8 af[4], bf[4];
        #pragma unroll
        for (int ni = 0; ni < 4; ++ni)
            bf[ni] = *(const s16x8*)(Wm1b + (((kt * 4 + quad) * 256) + colb + ni * 16) * 8);
        #pragma unroll
        for (int mi = 0; mi < 4; ++mi)
            af[mi] = *(const s16x8*)(As + (mi * 16 + mrow) * 264 + kt * 32 + quad * 8);
        #pragma unroll
        for (int mi = 0; mi < 4; ++mi)
            #pragma unroll
            for (int ni = 0; ni < 4; ++ni)
                acc[mi][ni] = __builtin_amdgcn_mfma_f32_16x16x32_bf16(af[mi], bf[ni], acc[mi][ni], 0, 0, 0);
    }

    #pragma unroll
    for (int mi = 0; mi < 4; ++mi)
        #pragma unroll
        for (int rg = 0; rg < 4; ++rg) {
            int row = row0 + mi * 16 + quad * 4 + rg;
            if (row >= 30000) continue;
            #pragma unroll
            for (int ni = 0; ni < 4; ++ni)
                Qb[row * 256 + colb + ni * 16] = f2bu(acc[mi][ni][rg]);
        }
}

// ---- fast-path edge aggregation (round-4 proven): one block per node,
// eattr@Wm1_bot on the MFMA pipe in 16-edge chunks, Q via coalesced gather,
// per-column register partials, shfl_xor cross-quad reduce, plain writes. ----
#define MAXD 96
__global__ __launch_bounds__(256) void edge_mfma_node_kernel(
    const u16* __restrict__ Qb, const void* __restrict__ eattr,
    const int* __restrict__ eidx,
    const u16* __restrict__ permLo, const u8* __restrict__ permHi,
    const u32* __restrict__ cursor,
    const u16* __restrict__ Wm1b, const void* __restrict__ bm1,
    const int* __restrict__ flag, float* __restrict__ aggP) {
    const int f32 = flag[0];
    const int n = blockIdx.x, tid = threadIdx.x;
    const int w = tid >> 6, lane = tid & 63, quad = lane >> 4, mrow = lane & 15;
    const int beg = (n > 0) ? (int)cursor[n - 1] : 0;
    const int end = (int)cursor[n];
    __shared__ int eids[MAXD];
    __shared__ int sorted_s[MAXD];
    __shared__ int srcs16[16];
    __shared__ __attribute__((aligned(16))) u16 Ae[16 * 40];   // 16 edges x K=32 (+pad)

    const int colb = w * 64 + mrow;
    // hoisted: B fragments (kt=8 slice) + bias, block-invariant
    s16x8 bf[4];
    float bm1c[4];
    #pragma unroll
    for (int ni = 0; ni < 4; ++ni) {
        bf[ni] = *(const s16x8*)(Wm1b + (((32 + quad) * 256) + colb + ni * 16) * 8);
        bm1c[ni] = ldv(bm1, colb + ni * 16, f32);
    }

    float psum[4] = {0.f, 0.f, 0.f, 0.f};
    const f32x4 fzero = {0.f, 0.f, 0.f, 0.f};

    for (int base = beg; base < end; base += MAXD) {
        int wcnt = end - base; if (wcnt > MAXD) wcnt = MAXD;
        if (tid < wcnt) {
            int si = base + tid;
            eids[tid] = (int)permLo[si] | ((int)permHi[si] << 16);
        }
        __syncthreads();
        if (tid < wcnt) {   // canonical rank sort: order independent of scatter order
            int key = eids[tid], r2 = 0;
            for (int j = 0; j < wcnt; ++j) r2 += (eids[j] < key);
            sorted_s[r2] = key;
        }
        __syncthreads();

        for (int cb = 0; cb < wcnt; cb += 16) {
            // stage a 16-edge chunk: eattr (bf16, zero-padded to K=32) + srcs
            {
                int row = tid >> 4, c = tid & 15;
                int gi = cb + row;
                int e = (gi < wcnt) ? sorted_s[gi] : -1;
                u16 v = 0;
                if (e >= 0 && c < 14) v = f2bu(ldv(eattr, e * 14 + c, f32));
                Ae[row * 40 + c] = v;
                Ae[row * 40 + 16 + c] = 0;
                if (c == 0) srcs16[row] = (e >= 0) ? eidx[e] : 0;
            }
            __syncthreads();

            s16x8 af = *(const s16x8*)(Ae + mrow * 40 + quad * 8);
            f32x4 acc[4];
            #pragma unroll
            for (int ni = 0; ni < 4; ++ni)
                acc[ni] = __builtin_amdgcn_mfma_f32_16x16x32_bf16(af, bf[ni], fzero, 0, 0, 0);

            #pragma unroll
            for (int rg = 0; rg < 4; ++rg) {
                int row = quad * 4 + rg;
                if (cb + row < wcnt) {
                    const u16* qrow = Qb + srcs16[row] * 256;
                    #pragma unroll
                    for (int ni = 0; ni < 4; ++ni) {
                        float q = b2f(qrow[colb + ni * 16]);
                        psum[ni] += fmaxf(acc[ni][rg] + bm1c[ni] + q, 0.0f);
                    }
                }
            }
            __syncthreads();   // protect Ae/srcs16 before next chunk restage
        }
    }

    // cross-quad reduction (rows of the tile live on lanes l, l^16, l^32)
    #pragma unroll
    for (int ni = 0; ni < 4; ++ni) {
        float v = psum[ni];
        v += __shfl_xor(v, 16, 64);
        v += __shfl_xor(v, 32, 64);
        psum[ni] = v;
    }
    if (quad == 0) {
        #pragma unroll
        for (int ni = 0; ni < 4; ++ni)
            aggP[n * 256 + colb + ni * 16] = psum[ni];
    }
}

// ---- FALLBACK edge kernel (round-10, proven): GEMM1 in-kernel, atomic aggP ----
__global__ __launch_bounds__(256) void edge_sorted_kernel(
    const u16* __restrict__ h0b, const void* __restrict__ eattr,
    const int* __restrict__ eidx,
    const u16* __restrict__ permLo, const u8* __restrict__ permHi,
    const u16* __restrict__ Wm1b,
    const void* __restrict__ bm1,
    const int* __restrict__ flag, float* __restrict__ aggP) {
    __shared__ __attribute__((aligned(16))) u16 As[64 * 296];
    __shared__ int dsh[64];
    const int f32 = flag[0];
    const int tid = threadIdx.x;
    const int w = tid >> 6, lane = tid & 63, quad = lane >> 4, mrow = lane & 15;
    const int eb0 = blockIdx.x * 64;
    const int colb = w * 64 + mrow;

    if (tid < 64) {
        int sj = eb0 + tid;
        int ee = (int)permLo[sj] | ((int)permHi[sj] << 16);
        dsh[tid] = eidx[480000 + ee];
    }
    {
        int r = tid >> 2, sub = tid & 3;
        int si = eb0 + r;
        int e = (int)permLo[si] | ((int)permHi[si] << 16);
        int src = eidx[e];
        const u16* hrow = h0b + src * 256;
        u16* arow = As + r * 296;
        #pragma unroll
        for (int j = 0; j < 8; ++j) {
            int c0 = sub * 64 + j * 8;
            *(s16x8*)(arow + c0) = *(const s16x8*)(hrow + c0);
        }
        if (sub == 0) {
            for (int c = 0; c < 14; ++c) arow[256 + c] = f2bu(ldv(eattr, e * 14 + c, f32));
            for (int c = 14; c < 40; ++c) arow[256 + c] = 0;
        }
    }
    __syncthreads();

    f32x4 acc[4][4];
    f32x4 fzero = {0.f, 0.f, 0.f, 0.f};
    #pragma unroll
    for (int mi = 0; mi < 4; ++mi)
        #pragma unroll
        for (int ni = 0; ni < 4; ++ni) acc[mi][ni] = fzero;

    for (int kt = 0; kt < 9; ++kt) {
        s16x8 af[4], bf[4];
        #pragma unroll
        for (int ni = 0; ni < 4; ++ni)
            bf[ni] = *(const s16x8*)(Wm1b + (((kt * 4 + quad) * 256) + colb + ni * 16) * 8);
        #pragma unroll
        for (int mi = 0; mi < 4; ++mi)
            af[mi] = *(const s16x8*)(As + (mi * 16 + mrow) * 296 + kt * 32 + quad * 8);
        #pragma unroll
        for (int mi = 0; mi < 4; ++mi)
            #pragma unroll
            for (int ni = 0; ni < 4; ++ni)
                acc[mi][ni] = __builtin_amdgcn_mfma_f32_16x16x32_bf16(af[mi], bf[ni], acc[mi][ni], 0, 0, 0);
    }

    float bm1c[4];
    #pragma unroll
    for (int ni = 0; ni < 4; ++ni) bm1c[ni] = ldv(bm1, colb + ni * 16, f32);
    __syncthreads();
    #pragma unroll
    for (int mi = 0; mi < 4; ++mi)
        #pragma unroll
        for (int ni = 0; ni < 4; ++ni)
            #pragma unroll
            for (int rg = 0; rg < 4; ++rg) {
                int row = mi * 16 + quad * 4 + rg;
                As[row * 296 + colb + ni * 16] = f2bu(fmaxf(acc[mi][ni][rg] + bm1c[ni], 0.0f));
            }
    __syncthreads();

    {
        int c = tid;
        float s = 0.0f;
        int cur = dsh[0];
        #pragma unroll 8
        for (int rr = 0; rr < 64; ++rr) {
            int d = dsh[rr];
            if (d != cur) { atomicAdd(&aggP[cur * 256 + c], s); s = 0.0f; cur = d; }
            s += b2f(As[rr * 296 + c]);
        }
        atomicAdd(&aggP[cur * 256 + c], s);
    }
}

// ---- fused node update: out = relu(h0@Wr + aggP@Wm2 + br + deg*bm2), in-place bf16 ----
__global__ __launch_bounds__(256) void node_dual_kernel(
    u16* __restrict__ h0b, const u16* __restrict__ Wrb, const u16* __restrict__ Wm2b,
    const void* __restrict__ br, const void* __restrict__ bm2,
    const float* __restrict__ aggP, const float* __restrict__ degf,
    const int* __restrict__ flag) {
    __shared__ __attribute__((aligned(16))) u16 As[64 * 264];
    const int f32 = flag[0];
    const int tid = threadIdx.x;
    const int w = tid >> 6, lane = tid & 63, quad = lane >> 4, mrow = lane & 15;
    const int row0 = blockIdx.x * 64;
    const int colb = w * 64 + mrow;
    const int r = tid >> 2, sub = tid & 3;

    {
        int row = row0 + r;
        u16* arow = As + r * 264;
        #pragma unroll
        for (int j = 0; j < 8; ++j) {
            int c0 = sub * 64 + j * 8;
            s16x8 v = {0, 0, 0, 0, 0, 0, 0, 0};
            if (row < 30000) v = *(const s16x8*)(h0b + row * 256 + c0);
            *(s16x8*)(arow + c0) = v;
        }
    }
    __syncthreads();

    f32x4 acc[4][4];
    f32x4 fzero = {0.f, 0.f, 0.f, 0.f};
    #pragma unroll
    for (int mi = 0; mi < 4; ++mi)
        #pragma unroll
        for (int ni = 0; ni < 4; ++ni) acc[mi][ni] = fzero;

    for (int kt = 0; kt < 8; ++kt) {
        s16x8 af[4], bf[4];
        #pragma unroll
        for (int ni = 0; ni < 4; ++ni)
            bf[ni] = *(const s16x8*)(Wrb + (((kt * 4 + quad) * 256) + colb + ni * 16) * 8);
        #pragma unroll
        for (int mi = 0; mi < 4; ++mi)
            af[mi] = *(const s16x8*)(As + (mi * 16 + mrow) * 264 + kt * 32 + quad * 8);
        #pragma unroll
        for (int mi = 0; mi < 4; ++mi)
            #pragma unroll
            for (int ni = 0; ni < 4; ++ni)
                acc[mi][ni] = __builtin_amdgcn_mfma_f32_16x16x32_bf16(af[mi], bf[ni], acc[mi][ni], 0, 0, 0);
    }
    __syncthreads();

    // restage aggP rows (f32 -> bf16), vectorized
    {
        int row = row0 + r;
        u16* arow = As + r * 264;
        #pragma unroll
        for (int j = 0; j < 8; ++j) {
            int c0 = sub * 64 + j * 8;
            s16x8 pk = {0, 0, 0, 0, 0, 0, 0, 0};
            if (row < 30000) {
                f32x4 a = *(const f32x4*)(aggP + row * 256 + c0);
                f32x4 b = *(const f32x4*)(aggP + row * 256 + c0 + 4);
                pk[0] = (short)f2bu(a[0]); pk[1] = (short)f2bu(a[1]);
                pk[2] = (short)f2bu(a[2]); pk[3] = (short)f2bu(a[3]);
                pk[4] = (short)f2bu(b[0]); pk[5] = (short)f2bu(b[1]);
                pk[6] = (short)f2bu(b[2]); pk[7] = (short)f2bu(b[3]);
            }
            *(s16x8*)(arow + c0) = pk;
        }
    }
    __syncthreads();

    for (int kt = 0; kt < 8; ++kt) {
        s16x8 af[4], bf[4];
        #pragma unroll
        for (int ni = 0; ni < 4; ++ni)
            bf[ni] = *(const s16x8*)(Wm2b + (((kt * 4 + quad) * 256) + colb + ni * 16) * 8);
        #pragma unroll
        for (int mi = 0; mi < 4; ++mi)
            af[mi] = *(const s16x8*)(As + (mi * 16 + mrow) * 264 + kt * 32 + quad * 8);
        #pragma unroll
        for (int mi = 0; mi < 4; ++mi)
            #pragma unroll
            for (int ni = 0; ni < 4; ++ni)
                acc[mi][ni] = __builtin_amdgcn_mfma_f32_16x16x32_bf16(af[mi], bf[ni], acc[mi][ni], 0, 0, 0);
    }

    #pragma unroll
    for (int mi = 0; mi < 4; ++mi)
        #pragma unroll
        for (int rg = 0; rg < 4; ++rg) {
            int row = row0 + mi * 16 + quad * 4 + rg;
            if (row >= 30000) continue;
            float dg = degf[row];
            #pragma unroll
            for (int ni = 0; ni < 4; ++ni) {
                int col = colb + ni * 16;
                float v = acc[mi][ni][rg] + ldv(br, col, f32) + dg * ldv(bm2, col, f32);
                h0b[row * 256 + col] = f2bu(fmaxf(v, 0.0f));
            }
        }
}

// ---- Set2Set gates via MFMA: 128 blocks (64x64 tiles, wave = 16 cols) ----
__global__ __launch_bounds__(256) void gates_mfma_kernel(
    const u16* __restrict__ Abuf, const u16* __restrict__ Wcatb,
    float* __restrict__ G) {
    const int tid = threadIdx.x;
    const int w = tid >> 6, lane = tid & 63, quad = lane >> 4, mrow = lane & 15;
    const int row0 = blockIdx.x * 64;
    const int col = blockIdx.y * 64 + w * 16 + mrow;

    f32x4 acc[4];
    f32x4 fzero = {0.f, 0.f, 0.f, 0.f};
    #pragma unroll
    for (int mi = 0; mi < 4; ++mi) acc[mi] = fzero;

    for (int kt = 0; kt < 24; ++kt) {
        s16x8 bfv = *(const s16x8*)(Wcatb + (((kt * 4 + quad) * 1024) + col) * 8);
        s16x8 af[4];
        #pragma unroll
        for (int mi = 0; mi < 4; ++mi)
            af[mi] = *(const s16x8*)(Abuf + (row0 + mi * 16 + mrow) * 768 + kt * 32 + quad * 8);
        #pragma unroll
        for (int mi = 0; mi < 4; ++mi)
            acc[mi] = __builtin_amdgcn_mfma_f32_16x16x32_bf16(af[mi], bfv, acc[mi], 0, 0, 0);
    }

    #pragma unroll
    for (int mi = 0; mi < 4; ++mi)
        #pragma unroll
        for (int rg = 0; rg < 4; ++rg)
            G[(row0 + mi * 16 + quad * 4 + rg) * 1024 + col] = acc[mi][rg];
}

// ---- fused LSTM + Set2Set attention: block b computes its own LSTM cell from
// G row b (gates -> c,h), keeps h in LDS, then e = out.h, segment softmax,
// r = sum a*out — one launch instead of two, no Hst round-trip inside. ----
#define GROWS 112
__global__ __launch_bounds__(256) void s2s_lstm_fused_kernel(
    const float* __restrict__ G, const void* __restrict__ bl,
    const int* __restrict__ flag, float* __restrict__ Cst, float* __restrict__ Hst,
    const u16* __restrict__ outb, const int* __restrict__ batch,
    float* __restrict__ Rst, u16* __restrict__ Abuf, float* __restrict__ ebuf) {
    __shared__ __attribute__((aligned(16))) u16 Ls[GROWS * 256];
    __shared__ __attribute__((aligned(16))) float hsh[256];
    __shared__ float esh[GROWS];
    __shared__ float red[256];
    const int b = blockIdx.x, tid = threadIdx.x;
    const int w = tid >> 6, lane = tid & 63;
    const int f32 = flag[0];

    // LSTM cell for graph b (identical math to the old lstm_kernel)
    {
        float gi = G[b * 1024 + tid]       + ldv(bl, tid, f32);
        float gf = G[b * 1024 + 256 + tid] + ldv(bl, 256 + tid, f32);
        float gg = G[b * 1024 + 512 + tid] + ldv(bl, 512 + tid, f32);
        float go = G[b * 1024 + 768 + tid] + ldv(bl, 768 + tid, f32);
        float c = Cst[b * 256 + tid];
        c = sigm(gf) * c + sigm(gi) * tanhf(gg);
        Cst[b * 256 + tid] = c;
        float h = sigm(go) * tanhf(c);
        Hst[b * 256 + tid] = h;
        u16 hb = f2bu(h);
        Abuf[b * 768 + tid] = hb;
        Abuf[b * 768 + 512 + tid] = hb;
        hsh[tid] = h;
    }
    const int n0 = lower_bound(batch, 30000, b);
    const int n1 = lower_bound(batch, 30000, b + 1);
    const int cnt = n1 - n0;
    __syncthreads();
    float r_out = 0.0f;
    if (cnt > 0 && cnt <= GROWS) {
        // stage graph rows (contiguous, coalesced)
        for (int idx = tid; idx < cnt * 32; idx += 256) {
            int i = idx >> 5, c8 = idx & 31;
            *(s16x8*)(Ls + i * 256 + c8 * 8) = *(const s16x8*)(outb + (n0 + i) * 256 + c8 * 8);
        }
        __syncthreads();
        // e per node: wave w handles nodes w, w+4, ...
        for (int i = w; i < cnt; i += 4) {
            s16x4 ov = *(const s16x4*)(Ls + i * 256 + lane * 4);
            f32x4 hv = *(const f32x4*)(hsh + lane * 4);
            float p = b2f((u16)ov[0]) * hv[0] + b2f((u16)ov[1]) * hv[1]
                    + b2f((u16)ov[2]) * hv[2] + b2f((u16)ov[3]) * hv[3];
            #pragma unroll
            for (int off = 1; off < 64; off <<= 1) p += __shfl_xor(p, off, 64);
            if (lane == 0) esh[i] = p;
        }
        __syncthreads();
        // softmax over esh[0..cnt)
        float m = -1e30f;
        for (int i = tid; i < cnt; i += 256) m = fmaxf(m, esh[i]);
        red[tid] = m; __syncthreads();
        for (int s = 128; s > 0; s >>= 1) { if (tid < s) red[tid] = fmaxf(red[tid], red[tid + s]); __syncthreads(); }
        m = red[0]; __syncthreads();
        float sl = 0.0f;
        for (int i = tid; i < cnt; i += 256) { float pe = expf(esh[i] - m); esh[i] = pe; sl += pe; }
        red[tid] = sl; __syncthreads();
        for (int s = 128; s > 0; s >>= 1) { if (tid < s) red[tid] += red[tid + s]; __syncthreads(); }
        float ssum = red[0]; __syncthreads();
        // weighted feature sum from LDS
        float acc = 0.0f;
        for (int i = 0; i < cnt; ++i) acc += esh[i] * b2f(Ls[i * 256 + tid]);
        r_out = acc / ssum;
    } else if (cnt > GROWS) {
        // fallback: compute e to global ebuf, then two-pass softmax from global
        for (int i = w; i < cnt; i += 4) {
            const u16* orow = outb + (n0 + i) * 256 + lane * 4;
            f32x4 hv = *(const f32x4*)(hsh + lane * 4);
            float p = b2f(orow[0]) * hv[0] + b2f(orow[1]) * hv[1]
                    + b2f(orow[2]) * hv[2] + b2f(orow[3]) * hv[3];
            #pragma unroll
            for (int off = 1; off < 64; off <<= 1) p += __shfl_xor(p, off, 64);
            if (lane == 0) ebuf[n0 + i] = p;
        }
        __syncthreads();
        float m = -1e30f;
        for (int n = n0 + tid; n < n1; n += 256) m = fmaxf(m, ebuf[n]);
        red[tid] = m; __syncthreads();
        for (int s = 128; s > 0; s >>= 1) { if (tid < s) red[tid] = fmaxf(red[tid], red[tid + s]); __syncthreads(); }
        m = red[0]; __syncthreads();
        float sl = 0.0f;
        for (int n = n0 + tid; n < n1; n += 256) sl += expf(ebuf[n] - m);
        red[tid] = sl; __syncthreads();
        for (int s = 128; s > 0; s >>= 1) { if (tid < s) red[tid] += red[tid + s]; __syncthreads(); }
        float ssum = red[0]; __syncthreads();
        float acc = 0.0f;
        for (int c0 = n0; c0 < n1; c0 += 256) {
            int nn = n1 - c0; if (nn > 256) nn = 256;
            __syncthreads();
            if (tid < nn) red[tid] = expf(ebuf[c0 + tid] - m);
            __syncthreads();
            for (int i = 0; i < nn; ++i) acc += red[i] * b2f(outb[(c0 + i) * 256 + tid]);
        }
        r_out = acc / ssum;
    }
    Rst[b * 256 + tid] = r_out;
    Abuf[b * 768 + 256 + tid] = f2bu(r_out);
}

// ---- readout + stage diagnostics ----
__global__ __launch_bounds__(256) void readout_kernel(const float* Hst, const float* Rst,
                                                      const void* W1, const void* b1,
                                                      const void* W2, const void* b2,
                                                      const u16* nodeout, const float* aggP,
                                                      const int* flag, void* out) {
    int f32 = flag[0];
    int b = blockIdx.x, tid = threadIdx.x;
    __shared__ float qs[512];
    __shared__ float red[256];
    qs[tid] = Hst[b * 256 + tid];
    qs[256 + tid] = Rst[b * 256 + tid];
    __syncthreads();
    float a = ldv(b1, tid, f32);
    for (int k = 0; k < 512; ++k) a += qs[k] * ldv(W1, k * 256 + tid, f32);
    a = fmaxf(a, 0.0f) * ldv(W2, tid, f32);
    red[tid] = a; __syncthreads();
    for (int s = 128; s > 0; s >>= 1) { if (tid < s) red[tid] += red[tid + s]; __syncthreads(); }
    if (tid == 0) {
        float D = 0.0f;
        if (b == 0) {
            float s1 = 0.0f, s2 = 0.0f, s3 = 0.0f;
            for (int i = 0; i < 256; ++i) {
                s1 += fabsf(b2f(nodeout[i]));
                s2 += fabsf(aggP[i]);
                s3 += fabsf(Rst[i]);
            }
            if (s1 < 1e-3f) D += 100.0f;
            if (s2 < 1e-3f) D += 200.0f;
            if (s3 < 1e-6f) D += 400.0f;
        }
        stv(out, b, red[0] + ldv(b2, 0, f32) + D, f32);
    }
}

// ---------------- workspace layout (bytes) ----------------
// INVARIANT: Abuf and G alias the aggP region (workspace reuse). aggP's last
// reader is node_dual_kernel; Abuf/G must only be written AFTER it runs.
#define OFF_FLAG 0
#define OFF_HST  64
#define OFF_RST  524352
#define OFF_CST  1048640
#define OFF_PLO  64
#define OFF_PHI  960064
#define OFF_CUR  1440064
#define OFF_WREG 1572928
#define OFF_WM1B (OFF_WREG)
#define OFF_WM2B (OFF_WREG + 147456)
#define OFF_WRB  (OFF_WREG + 278528)
#define OFF_WCAT (OFF_WREG + 409600)
#define OFF_E    3670080
#define OFF_AGG  3790144
#define OFF_ABUF (OFF_AGG + 1048576)
#define OFF_G    (OFF_AGG + 4194304)
#define OFF_H0B  34510144
#define WS_NEEDED 49870144
#define OFF_Q    49870144                 // fast path only: Q bf16 [30000x256]
#define WS_FAST  (49870144 + 15360000)

extern "C" __attribute__((visibility("default")))
void kernel_launch(void* const* d_in, const int* in_sizes, int n_in,
                   void* d_out, int out_size, void* d_ws, size_t ws_size,
                   hipStream_t stream) {
    char* ws = (char*)d_ws;
    int*   flag   = (int*)(ws + OFF_FLAG);
    float* Hst    = (float*)(ws + OFF_HST);
    float* Rst    = (float*)(ws + OFF_RST);
    float* Cst    = (float*)(ws + OFF_CST);
    u16*   permLo = (u16*)(ws + OFF_PLO);
    u8*    permHi = (u8*)(ws + OFF_PHI);
    u32*   cursor = (u32*)(ws + OFF_CUR);
    u16*   Wm1b   = (u16*)(ws + OFF_WM1B);
    u16*   Wm2b   = (u16*)(ws + OFF_WM2B);
    u16*   Wrb    = (u16*)(ws + OFF_WRB);
    u16*   Wcatb  = (u16*)(ws + OFF_WCAT);
    float* ebuf   = (float*)(ws + OFF_E);
    u32*   part   = (u32*)(ws + OFF_E);
    u32*   pexcl  = (u32*)(ws + OFF_E + 512);
    float* degf   = (float*)(ws + OFF_E);
    float* aggP   = (float*)(ws + OFF_AGG);
    u16*   Abuf   = (u16*)(ws + OFF_ABUF);
    float* G      = (float*)(ws + OFF_G);
    u16*   h0b    = (u16*)(ws + OFF_H0B);
    u16*   Qb     = (u16*)(ws + OFF_Q);

    detect_kernel<<<1, 256, 0, stream>>>(d_in[0], flag);

    bool sizes_ok = (n_in == 19)
        && in_sizes[0] == 30000 * 25
        && in_sizes[1] == 480000 * 14
        && in_sizes[4] == 270 * 256
        && in_sizes[10] == 512 * 1024
        && in_sizes[17] == 2 * 480000
        && in_sizes[18] == 30000;
    if (!sizes_ok) { fillv_kernel<<<2, 256, 0, stream>>>(d_out, flag, 1600.0f); return; }
    if (ws_size < (size_t)WS_NEEDED) { fillv_kernel<<<2, 256, 0, stream>>>(d_out, flag, 800.0f); return; }
    const bool fast = (ws_size >= (size_t)WS_FAST);

    fillv_kernel<<<2, 256, 0, stream>>>(d_out, flag, 3.0f);
    DMPNN_Change_678604832935_kernel<<<1, 64, 0, stream>>>((int*)(ws + OFF_G));

    const void* x     = d_in[0];
    const void* eattr = d_in[1];
    const void* W0    = d_in[2];
    const void* b0    = d_in[3];
    const void* Wm1   = d_in[4];
    const void* bm1   = d_in[5];
    const void* Wm2   = d_in[6];
    const void* bm2   = d_in[7];
    const void* Wr    = d_in[8];
    const void* br    = d_in[9];
    const void* Wih   = d_in[10];
    const void* Whh   = d_in[11];
    const void* bl    = d_in[12];
    const void* W1    = d_in[13];
    const void* b1    = d_in[14];
    const void* W2    = d_in[15];
    const void* b2    = d_in[16];
    const int* eidx   = (const int*)d_in[17];
    const int* batch  = (const int*)d_in[18];

    // all weight relayouts in one launch
    to_blocked_all<<<3872, 256, 0, stream>>>(Wm1, Wm2, Wr, Wih, Whh, flag,
                                             Wm1b, Wm2b, Wrb, Wcatb);

    lin0_kernel<<<3750, 256, 0, stream>>>(x, W0, b0, flag, h0b);

    // counting sort of edges by dst (CSR); integer atomics only
    zero_kernel<<<30, 256, 0, stream>>>((float*)cursor, 30000);
    hist_kernel<<<1875, 256, 0, stream>>>(eidx, cursor);
    scan1_kernel<<<118, 256, 0, stream>>>(cursor, part);
    scan2_kernel<<<1, 128, 0, stream>>>(part, pexcl, 118);
    scan3_kernel<<<118, 256, 0, stream>>>(cursor, pexcl);
    scatter_kernel<<<1875, 256, 0, stream>>>(eidx, cursor, permLo, permHi);
    deg_kernel<<<118, 256, 0, stream>>>(cursor, degf);

    if (fast) {
        // deterministic MFMA fast path: no float atomics, no aggP zeroing needed
        qgen_kernel<<<469, 256, 0, stream>>>(h0b, Wm1b, Qb);
        edge_mfma_node_kernel<<<30000, 256, 0, stream>>>(Qb, eattr, eidx, permLo, permHi,
                                                         cursor, Wm1b, bm1, flag, aggP);
    } else {
        zero_kernel<<<1024, 256, 0, stream>>>(aggP, 7680000);
        edge_sorted_kernel<<<7500, 256, 0, stream>>>(h0b, eattr, eidx, permLo, permHi,
                                                     Wm1b, bm1, flag, aggP);
    }
    node_dual_kernel<<<469, 256, 0, stream>>>(h0b, Wrb, Wm2b, br, bm2, aggP, degf, flag);

    // zero Cst + Abuf AFTER node_dual: Abuf aliases the aggP region (invariant above)
    zero2_kernel<<<256, 256, 0, stream>>>(Cst, 131072, (float*)Abuf, 196608);

    for (int s = 0; s < 3; ++s) {
        gates_mfma_kernel<<<dim3(8, 16), 256, 0, stream>>>(Abuf, Wcatb, G);
        s2s_lstm_fused_kernel<<<512, 256, 0, stream>>>(G, bl, flag, Cst, Hst,
                                                       h0b, batch, Rst, Abuf, ebuf);
    }
    readout_kernel<<<512, 256, 0, stream>>>(Hst, Rst, W1, b1, W2, b2, h0b, aggP, flag, d_out);
}

// Round 9
// 477.421 us; speedup vs baseline: 1.1300x; 1.0243x over previous
//
#include <hip/hip_runtime.h>

typedef unsigned short u16;
typedef unsigned char u8;
typedef unsigned int u32;
using s16x8 = __attribute__((ext_vector_type(8))) short;
using s16x4 = __attribute__((ext_vector_type(4))) short;
using f32x4 = __attribute__((ext_vector_type(4))) float;

#define DEV static __device__ __forceinline__

DEV float b2f(u16 u) { return __uint_as_float(((u32)u) << 16); }
DEV u16 f2bu(float f) {               // f32 -> bf16 bits, round-to-nearest-even
    u32 u = __float_as_uint(f);
    u32 r = (u + 0x7FFFu + ((u >> 16) & 1u)) >> 16;
    return (u16)r;
}
DEV float sigm(float x) { return 1.0f / (1.0f + expf(-x)); }

DEV float ldv(const void* p, int i, int f32flag) {
    if (f32flag) return ((const float*)p)[i];
    return b2f(((const u16*)p)[i]);
}
DEV void stv(void* p, int i, float v, int f32flag) {
    if (f32flag) ((float*)p)[i] = v;
    else ((u16*)p)[i] = f2bu(v);
}

DEV int lower_bound(const int* b, int n, int v) {
    int lo = 0, hi = n;
    while (lo < hi) { int mid = (lo + hi) >> 1; if (b[mid] < v) lo = mid + 1; else hi = mid; }
    return lo;
}

// identifier-named kernel from the stub skeleton (kept; harmless)
__global__ void DMPNN_Change_678604832935_kernel(int* p) {
    if (p && threadIdx.x == 0 && blockIdx.x == 0) p[0] = 1;
}

// ---- dtype sniffer ----
__global__ void detect_kernel(const void* x, int* flag) {
    __shared__ int cnt[128];
    int tid = threadIdx.x;
    if (tid < 128) {
        u16 v = ((const u16*)x)[tid];
        int e = (v >> 7) & 0xFF;
        cnt[tid] = (e >= 100 && e <= 141) ? 1 : 0;
    }
    __syncthreads();
    if (tid == 0) {
        int s = 0;
        for (int i = 0; i < 128; ++i) s += cnt[i];
        flag[0] = (s < 110) ? 1 : 0;   // 1 = float32 data, 0 = bf16 data
    }
}

__global__ void fillv_kernel(void* out, const int* flag, float v) {
    int i = blockIdx.x * 256 + threadIdx.x;
    if (i < 512) stv(out, i, v, flag[0]);
}

__global__ void zero_kernel(float* p, int n) {
    int i = blockIdx.x * 256 + threadIdx.x;
    int stride = gridDim.x * 256;
    for (; i < n; i += stride) p[i] = 0.0f;
}

// one launch zeroing two regions (Cst, Abuf) — runs AFTER node_dual because
// Abuf aliases the aggP region (workspace reuse); see layout invariant below.
__global__ void zero2_kernel(float* a, int na, float* b, int nb) {
    int i = blockIdx.x * 256 + threadIdx.x;
    int stride = gridDim.x * 256;
    for (int j = i; j < na; j += stride) a[j] = 0.0f;
    for (int j = i; j < nb; j += stride) b[j] = 0.0f;
}

// ---- counting sort of edges by dst: histogram -> scan -> scatter ----
// (integer atomics only: counts/positions are order-invariant; the permutation
//  order within a segment is canonicalized later by the rank sort)
__global__ void hist_kernel(const int* __restrict__ eidx, u32* __restrict__ cnt) {
    int i = blockIdx.x * 256 + threadIdx.x;
    if (i < 480000) atomicAdd(&cnt[eidx[480000 + i]], 1u);
}

__global__ void scan1_kernel(const u32* __restrict__ cnt, u32* __restrict__ part) {
    __shared__ u32 s[256];
    int i = blockIdx.x * 256 + threadIdx.x;
    s[threadIdx.x] = (i < 30000) ? cnt[i] : 0u;
    __syncthreads();
    for (int st = 128; st > 0; st >>= 1) {
        if (threadIdx.x < st) s[threadIdx.x] += s[threadIdx.x + st];
        __syncthreads();
    }
    if (threadIdx.x == 0) part[blockIdx.x] = s[0];
}

// wave-parallel exclusive scan of <=128 partials
__global__ void scan2_kernel(const u32* __restrict__ part, u32* __restrict__ pexcl, int nb) {
    int tid = threadIdx.x;              // blockDim = 128
    u32 v = (tid < nb) ? part[tid] : 0u;
    u32 x = v;
    #pragma unroll
    for (int off = 1; off < 64; off <<= 1) {
        u32 t = __shfl_up(x, off, 64);
        if ((tid & 63) >= off) x += t;
    }
    __shared__ u32 wsum;
    if (tid == 63) wsum = x;
    __syncthreads();
    u32 add = (tid >= 64) ? wsum : 0u;
    if (tid < nb) pexcl[tid] = x + add - v;   // exclusive
}

__global__ void scan3_kernel(u32* __restrict__ cursor, const u32* __restrict__ pexcl) {
    __shared__ u32 s[256];
    int b = blockIdx.x, tid = threadIdx.x;
    int i = b * 256 + tid;
    u32 v = (i < 30000) ? cursor[i] : 0u;
    s[tid] = v;
    __syncthreads();
    for (int off = 1; off < 256; off <<= 1) {
        u32 t = (tid >= off) ? s[tid - off] : 0u;
        __syncthreads();
        s[tid] += t;
        __syncthreads();
    }
    u32 excl = s[tid] - v + pexcl[b];
    if (i < 30000) cursor[i] = excl;
}

// scatter; optionally also records the edge's SRC (u16) at the sorted position,
// removing one dependent gather level from the edge kernel (srcW may be null).
__global__ void scatter_kernel(const int* __restrict__ eidx, u32* __restrict__ cursor,
                               u16* __restrict__ permLo, u8* __restrict__ permHi,
                               u16* __restrict__ srcW) {
    int i = blockIdx.x * 256 + threadIdx.x;
    if (i < 480000) {
        int d = eidx[480000 + i];
        u32 pos = atomicAdd(&cursor[d], 1u);
        permLo[pos] = (u16)(i & 0xFFFF);
        permHi[pos] = (u8)(i >> 16);
        if (srcW) srcW[pos] = (u16)eidx[i];
    }
}

// ---- ALL weights -> k-tile-blocked bf16 layouts in ONE launch ----
// regions: Wm1 (ktiles=9,N=256) | Wm2 (8,256) | Wr (8,256) | Wcat (24,N=1024)
__global__ void to_blocked_all(const void* Wm1, const void* Wm2, const void* Wr,
                               const void* Wih, const void* Whh, const int* flag,
                               u16* Wm1b, u16* Wm2b, u16* Wrb, u16* Wcatb) {
    const int T1 = 9 * 4 * 256 * 8;            // 73728
    const int T2 = T1 + 8 * 4 * 256 * 8;       // +65536
    const int T3 = T2 + 8 * 4 * 256 * 8;       // +65536
    const int T4 = T3 + 24 * 4 * 1024 * 8;     // +786432
    int idx = blockIdx.x * 256 + threadIdx.x;
    if (idx >= T4) return;
    int f32 = flag[0];
    if (idx < T3) {
        const void* src; u16* dst; int K; int l;
        if (idx < T1)      { src = Wm1; dst = Wm1b; K = 270; l = idx; }
        else if (idx < T2) { src = Wm2; dst = Wm2b; K = 256; l = idx - T1; }
        else               { src = Wr;  dst = Wrb;  K = 256; l = idx - T2; }
        int c = l & 7;
        int n = (l >> 3) & 255;
        int jk = l >> 11;
        int j = jk & 3, kt = jk >> 2;
        int k = kt * 32 + j * 8 + c;
        u16 v = 0;
        if (k < K) v = f2bu(ldv(src, k * 256 + n, f32));
        dst[l] = v;
    } else {
        int l = idx - T3;
        int c = l & 7;
        int n = (l >> 3) & 1023;
        int jk = l >> 13;
        int j = jk & 3, kt = jk >> 2;
        int k = kt * 32 + j * 8 + c;
        u16 v = 0;
        if (k < 512) v = f2bu(ldv(Wih, k * 1024 + n, f32));
        else if (k < 768) v = f2bu(ldv(Whh, (k - 512) * 1024 + n, f32));
        Wcatb[l] = v;
    }
}

// ---- lin0 (fallback path only): h0 = relu(x @ W0 + b0), 8 nodes/block ----
__global__ __launch_bounds__(256) void lin0_kernel(const void* x, const void* W0,
                                                   const void* b0, const int* flag,
                                                   u16* h0b) {
    int f32 = flag[0];
    int n0 = blockIdx.x * 8, tid = threadIdx.x;
    __shared__ float xs[8][26];
    if (tid < 200) {
        int nn = tid / 25, k = tid % 25;
        xs[nn][k] = ldv(x, (n0 + nn) * 25 + k, f32);
    }
    __syncthreads();
    float wr[25];
    #pragma unroll
    for (int k = 0; k < 25; ++k) wr[k] = ldv(W0, k * 256 + tid, f32);
    float bias = ldv(b0, tid, f32);
    #pragma unroll
    for (int nn = 0; nn < 8; ++nn) {
        float a = bias;
        #pragma unroll
        for (int k = 0; k < 25; ++k) a += xs[nn][k] * wr[k];
        h0b[(n0 + nn) * 256 + tid] = f2bu(fmaxf(a, 0.0f));
    }
}

// ---- FUSED lin0 + qgen: compute h0 tile (64 rows, VALU, K=25) into LDS,
// write h0b, then Q = h0 @ Wm1top via MFMA from the SAME LDS tile — saves the
// 15.4 MB h0b re-read and one launch. ----
__global__ __launch_bounds__(256) void lin0q_kernel(
    const void* x, const void* W0, const void* b0, const int* flag,
    const u16* __restrict__ Wm1b, u16* __restrict__ h0b, u16* __restrict__ Qb) {
    __shared__ __attribute__((aligned(16))) u16 As[64 * 264];
    __shared__ float xs[64][26];
    const int f32 = flag[0];
    const int tid = threadIdx.x;
    const int w = tid >> 6, lane = tid & 63, quad = lane >> 4, mrow = lane & 15;
    const int row0 = blockIdx.x * 64;
    const int colb = w * 64 + mrow;

    for (int idx = tid; idx < 64 * 25; idx += 256) {
        int i = idx / 25, k = idx - i * 25;
        int row = row0 + i;
        xs[i][k] = (row < 30000) ? ldv(x, row * 25 + k, f32) : 0.0f;
    }
    float wr[25];
    #pragma unroll
    for (int k = 0; k < 25; ++k) wr[k] = ldv(W0, k * 256 + tid, f32);
    float bias = ldv(b0, tid, f32);
    __syncthreads();
    for (int i = 0; i < 64; ++i) {
        float a = bias;
        #pragma unroll
        for (int k = 0; k < 25; ++k) a += xs[i][k] * wr[k];
        u16 hb = f2bu(fmaxf(a, 0.0f));
        As[i * 264 + tid] = hb;        // out-of-range rows hold relu(bias); their
        int row = row0 + i;            // MFMA results are discarded by the C-guard
        if (row < 30000) h0b[row * 256 + tid] = hb;
    }
    __syncthreads();

    f32x4 acc[4][4];
    f32x4 fzero = {0.f, 0.f, 0.f, 0.f};
    #pragma unroll
    for (int mi = 0; mi < 4; ++mi)
        #pragma unroll
        for (int ni = 0; ni < 4; ++ni) acc[mi][ni] = fzero;

    for (int kt = 0; kt < 8; ++kt) {
        s16x8 af[4], bf[4];
        #pragma unroll
        for (int ni = 0; ni < 4; ++ni)
            bf[ni] = *(const s16x8*)(Wm1b + (((kt * 4 + quad) * 256) + colb + ni * 16) * 8);
        #pragma unroll
        for (int mi = 0; mi < 4; ++mi)
            af[mi] = *(const s16x8*)(As + (mi * 16 + mrow) * 264 + kt * 32 + quad * 8);
        #pragma unroll
        for (int mi = 0; mi < 4; ++mi)
            #pragma unroll
            for (int ni = 0; ni < 4; ++ni)
                acc[mi][ni] = __builtin_amdgcn_mfma_f32_16x16x32_bf16(af[mi], bf[ni], acc[mi][ni], 0, 0, 0);
    }

    #pragma unroll
    for (int mi = 0; mi < 4; ++mi)
        #pragma unroll
        for (int rg = 0; rg < 4; ++rg) {
            int row = row0 + mi * 16 + quad * 4 + rg;
            if (row >= 30000) continue;
            #pragma unroll
            for (int ni = 0; ni < 4; ++ni)
                Qb[row * 256 + colb + ni * 16] = f2bu(acc[mi][ni][rg]);
        }
}

// ---- Q = h0 @ Wm1top (kept for fastlvl==1 path) ----
__global__ __launch_bounds__(256) void qgen_kernel(
    const u16* __restrict__ h0b, const u16* __restrict__ Wm1b,
    u16* __restrict__ Qb) {
    __shared__ __attribute__((aligned(16))) u16 As[64 * 264];
    const int tid = threadIdx.x;
    const int w = tid >> 6, lane = tid & 63, quad = lane >> 4, mrow = lane & 15;
    const int row0 = blockIdx.x * 64;
    const int colb = w * 64 + mrow;
    const int r = tid >> 2, sub = tid & 3;

    {
        int row = row0 + r;
        u16* arow = As + r * 264;
        #pragma unroll
        for (int j = 0; j < 8; ++j) {
            int c0 = sub * 64 + j * 8;
            s16x8 v = {0, 0, 0, 0, 0, 0, 0, 0};
            if (row < 30000) v = *(const s16x8*)(h0b + row * 256 + c0);
            *(s16x8*)(arow + c0) = v;
        }
    }
    __syncthreads();

    f32x4 acc[4][4];
    f32x4 fzero = {0.f, 0.f, 0.f, 0.f};
    #pragma unroll
    for (int mi = 0; mi < 4; ++mi)
        #pragma unroll
        for (int ni = 0; ni < 4; ++ni) acc[mi][ni] = fzero;

    for (int kt = 0; kt < 8; ++kt) {
        s16x8 af[4], bf[4];
        #pragma unroll
        for (int ni = 0; ni < 4; ++ni)
            bf[ni] = *(const s16x8*)(Wm1b + (((kt * 4 + quad) * 256) + colb + ni * 16) * 8);
        #pragma unroll
        for (int mi = 0; mi < 4; ++mi)
            af[mi] = *(const s16x8*)(As + (mi * 16 + mrow) * 264 + kt * 32 + quad * 8);
        #pragma unroll
        for (int mi = 0; mi < 4; ++mi)
            #pragma unroll
            for (int ni = 0; ni < 4; ++ni)
                acc[mi][ni] = __builtin_amdgcn_mfma_f32_16x16x32_bf16(af[mi], bf[ni], acc[mi][ni], 0, 0, 0);
    }

    #pragma unroll
    for (int mi = 0; mi < 4; ++mi)
        #pragma unroll
        for (int rg = 0; rg < 4; ++rg) {
            int row = row0 + mi * 16 + quad * 4 + rg;
            if (row >= 30000) continue;
            #pragma unroll
            for (int ni = 0; ni < 4; ++ni)
                Qb[row * 256 + colb + ni * 16] = f2bu(acc[mi][ni][rg]);
        }
}

// ---- edge aggregation v2 (fastlvl 2): like the proven node-centric kernel but
// (a) src comes pre-recorded from scatter (no eidx[e] dependent gather),
// (b) Q values prefetched into registers before the MFMA,
// (c) aggP written as bf16 (bit-identical: node_dual rounded to bf16 anyway). ----
#define MAXD 96
__global__ __launch_bounds__(256) void edge_mfma_node2_kernel(
    const u16* __restrict__ Qb, const void* __restrict__ eattr,
    const u16* __restrict__ srcW,
    const u16* __restrict__ permLo, const u8* __restrict__ permHi,
    const u32* __restrict__ cursor,
    const u16* __restrict__ Wm1b, const void* __restrict__ bm1,
    const int* __restrict__ flag, u16* __restrict__ aggB) {
    const int f32 = flag[0];
    const int n = blockIdx.x, tid = threadIdx.x;
    const int w = tid >> 6, lane = tid & 63, quad = lane >> 4, mrow = lane & 15;
    const int beg = (n > 0) ? (int)cursor[n - 1] : 0;
    const int end = (int)cursor[n];
    __shared__ int eids[MAXD];
    __shared__ int srcl[MAXD];
    __shared__ int sorted_s[MAXD];
    __shared__ int sortedSrc[MAXD];
    __shared__ __attribute__((aligned(16))) u16 Ae[16 * 40];   // 16 edges x K=32 (+pad)

    const int colb = w * 64 + mrow;
    s16x8 bf[4];
    float bm1c[4];
    #pragma unroll
    for (int ni = 0; ni < 4; ++ni) {
        bf[ni] = *(const s16x8*)(Wm1b + (((32 + quad) * 256) + colb + ni * 16) * 8);
        bm1c[ni] = ldv(bm1, colb + ni * 16, f32);
    }

    float psum[4] = {0.f, 0.f, 0.f, 0.f};
    const f32x4 fzero = {0.f, 0.f, 0.f, 0.f};

    for (int base = beg; base < end; base += MAXD) {
        int wcnt = end - base; if (wcnt > MAXD) wcnt = MAXD;
        if (tid < wcnt) {
            int si = base + tid;
            eids[tid] = (int)permLo[si] | ((int)permHi[si] << 16);
            srcl[tid] = (int)srcW[si];
        }
        __syncthreads();
        if (tid < wcnt) {   // canonical rank sort; carry src alongside the key
            int key = eids[tid], r2 = 0;
            for (int j = 0; j < wcnt; ++j) r2 += (eids[j] < key);
            sorted_s[r2] = key;
            sortedSrc[r2] = srcl[tid];
        }
        __syncthreads();

        for (int cb = 0; cb < wcnt; cb += 16) {
            // stage a 16-edge chunk of eattr (bf16, zero-padded to K=32)
            {
                int row = tid >> 4, c = tid & 15;
                int gi = cb + row;
                int e = (gi < wcnt) ? sorted_s[gi] : -1;
                u16 v = 0;
                if (e >= 0 && c < 14) v = f2bu(ldv(eattr, e * 14 + c, f32));
                Ae[row * 40 + c] = v;
                Ae[row * 40 + 16 + c] = 0;
            }
            __syncthreads();

            // prefetch Q values for this quad's rows (independent of the MFMA)
            float qv[4][4];
            #pragma unroll
            for (int rg = 0; rg < 4; ++rg) {
                int gi = cb + quad * 4 + rg;
                int sidx = (gi < wcnt) ? sortedSrc[gi] : 0;
                const u16* qrow = Qb + sidx * 256;
                #pragma unroll
                for (int ni = 0; ni < 4; ++ni)
                    qv[rg][ni] = b2f(qrow[colb + ni * 16]);
            }

            s16x8 af = *(const s16x8*)(Ae + mrow * 40 + quad * 8);
            f32x4 acc[4];
            #pragma unroll
            for (int ni = 0; ni < 4; ++ni)
                acc[ni] = __builtin_amdgcn_mfma_f32_16x16x32_bf16(af, bf[ni], fzero, 0, 0, 0);

            #pragma unroll
            for (int rg = 0; rg < 4; ++rg) {
                if (cb + quad * 4 + rg < wcnt) {
                    #pragma unroll
                    for (int ni = 0; ni < 4; ++ni)
                        psum[ni] += fmaxf(acc[ni][rg] + bm1c[ni] + qv[rg][ni], 0.0f);
                }
            }
            __syncthreads();   // protect Ae before next chunk restage
        }
    }

    #pragma unroll
    for (int ni = 0; ni < 4; ++ni) {
        float v = psum[ni];
        v += __shfl_xor(v, 16, 64);
        v += __shfl_xor(v, 32, 64);
        psum[ni] = v;
    }
    if (quad == 0) {
        #pragma unroll
        for (int ni = 0; ni < 4; ++ni)
            aggB[n * 256 + colb + ni * 16] = f2bu(psum[ni]);
    }
}

// ---- edge aggregation v1 (fastlvl 1, round-4 proven): f32 aggP ----
__global__ __launch_bounds__(256) void edge_mfma_node_kernel(
    const u16* __restrict__ Qb, const void* __restrict__ eattr,
    const int* __restrict__ eidx,
    const u16* __restrict__ permLo, const u8* __restrict__ permHi,
    const u32* __restrict__ cursor,
    const u16* __restrict__ Wm1b, const void* __restrict__ bm1,
    const int* __restrict__ flag, float* __restrict__ aggP) {
    const int f32 = flag[0];
    const int n = blockIdx.x, tid = threadIdx.x;
    const int w = tid >> 6, lane = tid & 63, quad = lane >> 4, mrow = lane & 15;
    const int beg = (n > 0) ? (int)cursor[n - 1] : 0;
    const int end = (int)cursor[n];
    __shared__ int eids[MAXD];
    __shared__ int sorted_s[MAXD];
    __shared__ int srcs16[16];
    __shared__ __attribute__((aligned(16))) u16 Ae[16 * 40];

    const int colb = w * 64 + mrow;
    s16x8 bf[4];
    float bm1c[4];
    #pragma unroll
    for (int ni = 0; ni < 4; ++ni) {
        bf[ni] = *(const s16x8*)(Wm1b + (((32 + quad) * 256) + colb + ni * 16) * 8);
        bm1c[ni] = ldv(bm1, colb + ni * 16, f32);
    }

    float psum[4] = {0.f, 0.f, 0.f, 0.f};
    const f32x4 fzero = {0.f, 0.f, 0.f, 0.f};

    for (int base = beg; base < end; base += MAXD) {
        int wcnt = end - base; if (wcnt > MAXD) wcnt = MAXD;
        if (tid < wcnt) {
            int si = base + tid;
            eids[tid] = (int)permLo[si] | ((int)permHi[si] << 16);
        }
        __syncthreads();
        if (tid < wcnt) {
            int key = eids[tid], r2 = 0;
            for (int j = 0; j < wcnt; ++j) r2 += (eids[j] < key);
            sorted_s[r2] = key;
        }
        __syncthreads();

        for (int cb = 0; cb < wcnt; cb += 16) {
            {
                int row = tid >> 4, c = tid & 15;
                int gi = cb + row;
                int e = (gi < wcnt) ? sorted_s[gi] : -1;
                u16 v = 0;
                if (e >= 0 && c < 14) v = f2bu(ldv(eattr, e * 14 + c, f32));
                Ae[row * 40 + c] = v;
                Ae[row * 40 + 16 + c] = 0;
                if (c == 0) srcs16[row] = (e >= 0) ? eidx[e] : 0;
            }
            __syncthreads();

            s16x8 af = *(const s16x8*)(Ae + mrow * 40 + quad * 8);
            f32x4 acc[4];
            #pragma unroll
            for (int ni = 0; ni < 4; ++ni)
                acc[ni] = __builtin_amdgcn_mfma_f32_16x16x32_bf16(af, bf[ni], fzero, 0, 0, 0);

            #pragma unroll
            for (int rg = 0; rg < 4; ++rg) {
                int row = quad * 4 + rg;
                if (cb + row < wcnt) {
                    const u16* qrow = Qb + srcs16[row] * 256;
                    #pragma unroll
                    for (int ni = 0; ni < 4; ++ni) {
                        float q = b2f(qrow[colb + ni * 16]);
                        psum[ni] += fmaxf(acc[ni][rg] + bm1c[ni] + q, 0.0f);
                    }
                }
            }
            __syncthreads();
        }
    }

    #pragma unroll
    for (int ni = 0; ni < 4; ++ni) {
        float v = psum[ni];
        v += __shfl_xor(v, 16, 64);
        v += __shfl_xor(v, 32, 64);
        psum[ni] = v;
    }
    if (quad == 0) {
        #pragma unroll
        for (int ni = 0; ni < 4; ++ni)
            aggP[n * 256 + colb + ni * 16] = psum[ni];
    }
}

// ---- FALLBACK edge kernel: GEMM1 in-kernel, atomic f32 aggP ----
__global__ __launch_bounds__(256) void edge_sorted_kernel(
    const u16* __restrict__ h0b, const void* __restrict__ eattr,
    const int* __restrict__ eidx,
    const u16* __restrict__ permLo, const u8* __restrict__ permHi,
    const u16* __restrict__ Wm1b,
    const void* __restrict__ bm1,
    const int* __restrict__ flag, float* __restrict__ aggP) {
    __shared__ __attribute__((aligned(16))) u16 As[64 * 296];
    __shared__ int dsh[64];
    const int f32 = flag[0];
    const int tid = threadIdx.x;
    const int w = tid >> 6, lane = tid & 63, quad = lane >> 4, mrow = lane & 15;
    const int eb0 = blockIdx.x * 64;
    const int colb = w * 64 + mrow;

    if (tid < 64) {
        int sj = eb0 + tid;
        int ee = (int)permLo[sj] | ((int)permHi[sj] << 16);
        dsh[tid] = eidx[480000 + ee];
    }
    {
        int r = tid >> 2, sub = tid & 3;
        int si = eb0 + r;
        int e = (int)permLo[si] | ((int)permHi[si] << 16);
        int src = eidx[e];
        const u16* hrow = h0b + src * 256;
        u16* arow = As + r * 296;
        #pragma unroll
        for (int j = 0; j < 8; ++j) {
            int c0 = sub * 64 + j * 8;
            *(s16x8*)(arow + c0) = *(const s16x8*)(hrow + c0);
        }
        if (sub == 0) {
            for (int c = 0; c < 14; ++c) arow[256 + c] = f2bu(ldv(eattr, e * 14 + c, f32));
            for (int c = 14; c < 40; ++c) arow[256 + c] = 0;
        }
    }
    __syncthreads();

    f32x4 acc[4][4];
    f32x4 fzero = {0.f, 0.f, 0.f, 0.f};
    #pragma unroll
    for (int mi = 0; mi < 4; ++mi)
        #pragma unroll
        for (int ni = 0; ni < 4; ++ni) acc[mi][ni] = fzero;

    for (int kt = 0; kt < 9; ++kt) {
        s16x8 af[4], bf[4];
        #pragma unroll
        for (int ni = 0; ni < 4; ++ni)
            bf[ni] = *(const s16x8*)(Wm1b + (((kt * 4 + quad) * 256) + colb + ni * 16) * 8);
        #pragma unroll
        for (int mi = 0; mi < 4; ++mi)
            af[mi] = *(const s16x8*)(As + (mi * 16 + mrow) * 296 + kt * 32 + quad * 8);
        #pragma unroll
        for (int mi = 0; mi < 4; ++mi)
            #pragma unroll
            for (int ni = 0; ni < 4; ++ni)
                acc[mi][ni] = __builtin_amdgcn_mfma_f32_16x16x32_bf16(af[mi], bf[ni], acc[mi][ni], 0, 0, 0);
    }

    float bm1c[4];
    #pragma unroll
    for (int ni = 0; ni < 4; ++ni) bm1c[ni] = ldv(bm1, colb + ni * 16, f32);
    __syncthreads();
    #pragma unroll
    for (int mi = 0; mi < 4; ++mi)
        #pragma unroll
        for (int ni = 0; ni < 4; ++ni)
            #pragma unroll
            for (int rg = 0; rg < 4; ++rg) {
                int row = mi * 16 + quad * 4 + rg;
                As[row * 296 + colb + ni * 16] = f2bu(fmaxf(acc[mi][ni][rg] + bm1c[ni], 0.0f));
            }
    __syncthreads();

    {
        int c = tid;
        float s = 0.0f;
        int cur = dsh[0];
        #pragma unroll 8
        for (int rr = 0; rr < 64; ++rr) {
            int d = dsh[rr];
            if (d != cur) { atomicAdd(&aggP[cur * 256 + c], s); s = 0.0f; cur = d; }
            s += b2f(As[rr * 296 + c]);
        }
        atomicAdd(&aggP[cur * 256 + c], s);
    }
}

// ---- fused node update: out = relu(h0@Wr + agg@Wm2 + br + deg*bm2), in-place bf16.
// agg may be bf16 (fast2) or f32 (other paths); deg computed from cursor. ----
__global__ __launch_bounds__(256) void node_dual_kernel(
    u16* __restrict__ h0b, const u16* __restrict__ Wrb, const u16* __restrict__ Wm2b,
    const void* __restrict__ br, const void* __restrict__ bm2,
    const void* __restrict__ aggV, int agg_bf16,
    const u32* __restrict__ cursor,
    const int* __restrict__ flag) {
    __shared__ __attribute__((aligned(16))) u16 As[64 * 264];
    const int f32 = flag[0];
    const int tid = threadIdx.x;
    const int w = tid >> 6, lane = tid & 63, quad = lane >> 4, mrow = lane & 15;
    const int row0 = blockIdx.x * 64;
    const int colb = w * 64 + mrow;
    const int r = tid >> 2, sub = tid & 3;

    {
        int row = row0 + r;
        u16* arow = As + r * 264;
        #pragma unroll
        for (int j = 0; j < 8; ++j) {
            int c0 = sub * 64 + j * 8;
            s16x8 v = {0, 0, 0, 0, 0, 0, 0, 0};
            if (row < 30000) v = *(const s16x8*)(h0b + row * 256 + c0);
            *(s16x8*)(arow + c0) = v;
        }
    }
    __syncthreads();

    f32x4 acc[4][4];
    f32x4 fzero = {0.f, 0.f, 0.f, 0.f};
    #pragma unroll
    for (int mi = 0; mi < 4; ++mi)
        #pragma unroll
        for (int ni = 0; ni < 4; ++ni) acc[mi][ni] = fzero;

    for (int kt = 0; kt < 8; ++kt) {
        s16x8 af[4], bf[4];
        #pragma unroll
        for (int ni = 0; ni < 4; ++ni)
            bf[ni] = *(const s16x8*)(Wrb + (((kt * 4 + quad) * 256) + colb + ni * 16) * 8);
        #pragma unroll
        for (int mi = 0; mi < 4; ++mi)
            af[mi] = *(const s16x8*)(As + (mi * 16 + mrow) * 264 + kt * 32 + quad * 8);
        #pragma unroll
        for (int mi = 0; mi < 4; ++mi)
            #pragma unroll
            for (int ni = 0; ni < 4; ++ni)
                acc[mi][ni] = __builtin_amdgcn_mfma_f32_16x16x32_bf16(af[mi], bf[ni], acc[mi][ni], 0, 0, 0);
    }
    __syncthreads();

    // restage agg rows into As (bf16)
    {
        int row = row0 + r;
        u16* arow = As + r * 264;
        if (agg_bf16) {
            const u16* aggB = (const u16*)aggV;
            #pragma unroll
            for (int j = 0; j < 8; ++j) {
                int c0 = sub * 64 + j * 8;
                s16x8 v = {0, 0, 0, 0, 0, 0, 0, 0};
                if (row < 30000) v = *(const s16x8*)(aggB + row * 256 + c0);
                *(s16x8*)(arow + c0) = v;
            }
        } else {
            const float* aggP = (const float*)aggV;
            #pragma unroll
            for (int j = 0; j < 8; ++j) {
                int c0 = sub * 64 + j * 8;
                s16x8 pk = {0, 0, 0, 0, 0, 0, 0, 0};
                if (row < 30000) {
                    f32x4 a = *(const f32x4*)(aggP + row * 256 + c0);
                    f32x4 b = *(const f32x4*)(aggP + row * 256 + c0 + 4);
                    pk[0] = (short)f2bu(a[0]); pk[1] = (short)f2bu(a[1]);
                    pk[2] = (short)f2bu(a[2]); pk[3] = (short)f2bu(a[3]);
                    pk[4] = (short)f2bu(b[0]); pk[5] = (short)f2bu(b[1]);
                    pk[6] = (short)f2bu(b[2]); pk[7] = (short)f2bu(b[3]);
                }
                *(s16x8*)(arow + c0) = pk;
            }
        }
    }
    __syncthreads();

    for (int kt = 0; kt < 8; ++kt) {
        s16x8 af[4], bf[4];
        #pragma unroll
        for (int ni = 0; ni < 4; ++ni)
            bf[ni] = *(const s16x8*)(Wm2b + (((kt * 4 + quad) * 256) + colb + ni * 16) * 8);
        #pragma unroll
        for (int mi = 0; mi < 4; ++mi)
            af[mi] = *(const s16x8*)(As + (mi * 16 + mrow) * 264 + kt * 32 + quad * 8);
        #pragma unroll
        for (int mi = 0; mi < 4; ++mi)
            #pragma unroll
            for (int ni = 0; ni < 4; ++ni)
                acc[mi][ni] = __builtin_amdgcn_mfma_f32_16x16x32_bf16(af[mi], bf[ni], acc[mi][ni], 0, 0, 0);
    }

    #pragma unroll
    for (int mi = 0; mi < 4; ++mi)
        #pragma unroll
        for (int rg = 0; rg < 4; ++rg) {
            int row = row0 + mi * 16 + quad * 4 + rg;
            if (row >= 30000) continue;
            float dg = (float)(cursor[row] - (row > 0 ? cursor[row - 1] : 0u));
            #pragma unroll
            for (int ni = 0; ni < 4; ++ni) {
                int col = colb + ni * 16;
                float v = acc[mi][ni][rg] + ldv(br, col, f32) + dg * ldv(bm2, col, f32);
                h0b[row * 256 + col] = f2bu(fmaxf(v, 0.0f));
            }
        }
}

// ---- Set2Set gates via MFMA: 128 blocks (64x64 tiles, wave = 16 cols) ----
__global__ __launch_bounds__(256) void gates_mfma_kernel(
    const u16* __restrict__ Abuf, const u16* __restrict__ Wcatb,
    float* __restrict__ G) {
    const int tid = threadIdx.x;
    const int w = tid >> 6, lane = tid & 63, quad = lane >> 4, mrow = lane & 15;
    const int row0 = blockIdx.x * 64;
    const int col = blockIdx.y * 64 + w * 16 + mrow;

    f32x4 acc[4];
    f32x4 fzero = {0.f, 0.f, 0.f, 0.f};
    #pragma unroll
    for (int mi = 0; mi < 4; ++mi) acc[mi] = fzero;

    for (int kt = 0; kt < 24; ++kt) {
        s16x8 bfv = *(const s16x8*)(Wcatb + (((kt * 4 + quad) * 1024) + col) * 8);
        s16x8 af[4];
        #pragma unroll
        for (int mi = 0; mi < 4; ++mi)
            af[mi] = *(const s16x8*)(Abuf + (row0 + mi * 16 + mrow) * 768 + kt * 32 + quad * 8);
        #pragma unroll
        for (int mi = 0; mi < 4; ++mi)
            acc[mi] = __builtin_amdgcn_mfma_f32_16x16x32_bf16(af[mi], bfv, acc[mi], 0, 0, 0);
    }

    #pragma unroll
    for (int mi = 0; mi < 4; ++mi)
        #pragma unroll
        for (int rg = 0; rg < 4; ++rg)
            G[(row0 + mi * 16 + quad * 4 + rg) * 1024 + col] = acc[mi][rg];
}

// ---- fused LSTM + Set2Set attention ----
#define GROWS 112
__global__ __launch_bounds__(256) void s2s_lstm_fused_kernel(
    const float* __restrict__ G, const void* __restrict__ bl,
    const int* __restrict__ flag, float* __restrict__ Cst, float* __restrict__ Hst,
    const u16* __restrict__ outb, const int* __restrict__ batch,
    float* __restrict__ Rst, u16* __restrict__ Abuf, float* __restrict__ ebuf) {
    __shared__ __attribute__((aligned(16))) u16 Ls[GROWS * 256];
    __shared__ __attribute__((aligned(16))) float hsh[256];
    __shared__ float esh[GROWS];
    __shared__ float red[256];
    const int b = blockIdx.x, tid = threadIdx.x;
    const int w = tid >> 6, lane = tid & 63;
    const int f32 = flag[0];

    // LSTM cell for graph b (identical math to the old lstm_kernel)
    {
        float gi = G[b * 1024 + tid]       + ldv(bl, tid, f32);
        float gf = G[b * 1024 + 256 + tid] + ldv(bl, 256 + tid, f32);
        float gg = G[b * 1024 + 512 + tid] + ldv(bl, 512 + tid, f32);
        float go = G[b * 1024 + 768 + tid] + ldv(bl, 768 + tid, f32);
        float c = Cst[b * 256 + tid];
        c = sigm(gf) * c + sigm(gi) * tanhf(gg);
        Cst[b * 256 + tid] = c;
        float h = sigm(go) * tanhf(c);
        Hst[b * 256 + tid] = h;
        u16 hb = f2bu(h);
        Abuf[b * 768 + tid] = hb;
        Abuf[b * 768 + 512 + tid] = hb;
        hsh[tid] = h;
    }
    const int n0 = lower_bound(batch, 30000, b);
    const int n1 = lower_bound(batch, 30000, b + 1);
    const int cnt = n1 - n0;
    __syncthreads();
    float r_out = 0.0f;
    if (cnt > 0 && cnt <= GROWS) {
        for (int idx = tid; idx < cnt * 32; idx += 256) {
            int i = idx >> 5, c8 = idx & 31;
            *(s16x8*)(Ls + i * 256 + c8 * 8) = *(const s16x8*)(outb + (n0 + i) * 256 + c8 * 8);
        }
        __syncthreads();
        for (int i = w; i < cnt; i += 4) {
            s16x4 ov = *(const s16x4*)(Ls + i * 256 + lane * 4);
            f32x4 hv = *(const f32x4*)(hsh + lane * 4);
            float p = b2f((u16)ov[0]) * hv[0] + b2f((u16)ov[1]) * hv[1]
                    + b2f((u16)ov[2]) * hv[2] + b2f((u16)ov[3]) * hv[3];
            #pragma unroll
            for (int off = 1; off < 64; off <<= 1) p += __shfl_xor(p, off, 64);
            if (lane == 0) esh[i] = p;
        }
        __syncthreads();
        float m = -1e30f;
        for (int i = tid; i < cnt; i += 256) m = fmaxf(m, esh[i]);
        red[tid] = m; __syncthreads();
        for (int s = 128; s > 0; s >>= 1) { if (tid < s) red[tid] = fmaxf(red[tid], red[tid + s]); __syncthreads(); }
        m = red[0]; __syncthreads();
        float sl = 0.0f;
        for (int i = tid; i < cnt; i += 256) { float pe = expf(esh[i] - m); esh[i] = pe; sl += pe; }
        red[tid] = sl; __syncthreads();
        for (int s = 128; s > 0; s >>= 1) { if (tid < s) red[tid] += red[tid + s]; __syncthreads(); }
        float ssum = red[0]; __syncthreads();
        float acc = 0.0f;
        for (int i = 0; i < cnt; ++i) acc += esh[i] * b2f(Ls[i * 256 + tid]);
        r_out = acc / ssum;
    } else if (cnt > GROWS) {
        for (int i = w; i < cnt; i += 4) {
            const u16* orow = outb + (n0 + i) * 256 + lane * 4;
            f32x4 hv = *(const f32x4*)(hsh + lane * 4);
            float p = b2f(orow[0]) * hv[0] + b2f(orow[1]) * hv[1]
                    + b2f(orow[2]) * hv[2] + b2f(orow[3]) * hv[3];
            #pragma unroll
            for (int off = 1; off < 64; off <<= 1) p += __shfl_xor(p, off, 64);
            if (lane == 0) ebuf[n0 + i] = p;
        }
        __syncthreads();
        float m = -1e30f;
        for (int n = n0 + tid; n < n1; n += 256) m = fmaxf(m, ebuf[n]);
        red[tid] = m; __syncthreads();
        for (int s = 128; s > 0; s >>= 1) { if (tid < s) red[tid] = fmaxf(red[tid], red[tid + s]); __syncthreads(); }
        m = red[0]; __syncthreads();
        float sl = 0.0f;
        for (int n = n0 + tid; n < n1; n += 256) sl += expf(ebuf[n] - m);
        red[tid] = sl; __syncthreads();
        for (int s = 128; s > 0; s >>= 1) { if (tid < s) red[tid] += red[tid + s]; __syncthreads(); }
        float ssum = red[0]; __syncthreads();
        float acc = 0.0f;
        for (int c0 = n0; c0 < n1; c0 += 256) {
            int nn = n1 - c0; if (nn > 256) nn = 256;
            __syncthreads();
            if (tid < nn) red[tid] = expf(ebuf[c0 + tid] - m);
            __syncthreads();
            for (int i = 0; i < nn; ++i) acc += red[i] * b2f(outb[(c0 + i) * 256 + tid]);
        }
        r_out = acc / ssum;
    }
    Rst[b * 256 + tid] = r_out;
    Abuf[b * 768 + 256 + tid] = f2bu(r_out);
}

// ---- readout + stage diagnostics (agg format aware) ----
__global__ __launch_bounds__(256) void readout_kernel(const float* Hst, const float* Rst,
                                                      const void* W1, const void* b1,
                                                      const void* W2, const void* b2,
                                                      const u16* nodeout, const void* aggV,
                                                      int agg_bf16,
                                                      const int* flag, void* out) {
    int f32 = flag[0];
    int b = blockIdx.x, tid = threadIdx.x;
    __shared__ float qs[512];
    __shared__ float red[256];
    qs[tid] = Hst[b * 256 + tid];
    qs[256 + tid] = Rst[b * 256 + tid];
    __syncthreads();
    float a = ldv(b1, tid, f32);
    for (int k = 0; k < 512; ++k) a += qs[k] * ldv(W1, k * 256 + tid, f32);
    a = fmaxf(a, 0.0f) * ldv(W2, tid, f32);
    red[tid] = a; __syncthreads();
    for (int s = 128; s > 0; s >>= 1) { if (tid < s) red[tid] += red[tid + s]; __syncthreads(); }
    if (tid == 0) {
        float D = 0.0f;
        if (b == 0) {
            float s1 = 0.0f, s2 = 0.0f, s3 = 0.0f;
            for (int i = 0; i < 256; ++i) {
                s1 += fabsf(b2f(nodeout[i]));
                s2 += agg_bf16 ? fabsf(b2f(((const u16*)aggV)[i]))
                               : fabsf(((const float*)aggV)[i]);
                s3 += fabsf(Rst[i]);
            }
            if (s1 < 1e-3f) D += 100.0f;
            if (s2 < 1e-3f) D += 200.0f;
            if (s3 < 1e-6f) D += 400.0f;
        }
        stv(out, b, red[0] + ldv(b2, 0, f32) + D, f32);
    }
}

// ---------------- workspace layout (bytes) ----------------
// INVARIANT: Abuf and G alias the aggP region (workspace reuse). aggP's last
// readers are node_dual_kernel (+ readout diagnostics, first 512 B only);
// Abuf/G must only be written AFTER node_dual runs.
#define OFF_FLAG 0
#define OFF_HST  64
#define OFF_RST  524352
#define OFF_CST  1048640
#define OFF_PLO  64
#define OFF_PHI  960064
#define OFF_CUR  1440064
#define OFF_WREG 1572928
#define OFF_WM1B (OFF_WREG)
#define OFF_WM2B (OFF_WREG + 147456)
#define OFF_WRB  (OFF_WREG + 278528)
#define OFF_WCAT (OFF_WREG + 409600)
#define OFF_E    3670080
#define OFF_AGG  3790144
#define OFF_ABUF (OFF_AGG + 1048576)
#define OFF_G    (OFF_AGG + 4194304)
#define OFF_H0B  34510144
#define WS_NEEDED 49870144
#define OFF_Q    49870144                 // fast path: Q bf16 [30000x256]
#define WS_FAST  (49870144 + 15360000)
#define OFF_SRC  (OFF_Q + 15360000)       // fast2: src u16 per sorted edge
#define WS_FAST2 (OFF_SRC + 960000)

extern "C" __attribute__((visibility("default")))
void kernel_launch(void* const* d_in, const int* in_sizes, int n_in,
                   void* d_out, int out_size, void* d_ws, size_t ws_size,
                   hipStream_t stream) {
    char* ws = (char*)d_ws;
    int*   flag   = (int*)(ws + OFF_FLAG);
    float* Hst    = (float*)(ws + OFF_HST);
    float* Rst    = (float*)(ws + OFF_RST);
    float* Cst    = (float*)(ws + OFF_CST);
    u16*   permLo = (u16*)(ws + OFF_PLO);
    u8*    permHi = (u8*)(ws + OFF_PHI);
    u32*   cursor = (u32*)(ws + OFF_CUR);
    u16*   Wm1b   = (u16*)(ws + OFF_WM1B);
    u16*   Wm2b   = (u16*)(ws + OFF_WM2B);
    u16*   Wrb    = (u16*)(ws + OFF_WRB);
    u16*   Wcatb  = (u16*)(ws + OFF_WCAT);
    float* ebuf   = (float*)(ws + OFF_E);
    u32*   part   = (u32*)(ws + OFF_E);
    u32*   pexcl  = (u32*)(ws + OFF_E + 512);
    float* aggP   = (float*)(ws + OFF_AGG);
    u16*   Abuf   = (u16*)(ws + OFF_ABUF);
    float* G      = (float*)(ws + OFF_G);
    u16*   h0b    = (u16*)(ws + OFF_H0B);
    u16*   Qb     = (u16*)(ws + OFF_Q);
    u16*   srcW   = (u16*)(ws + OFF_SRC);

    detect_kernel<<<1, 256, 0, stream>>>(d_in[0], flag);

    bool sizes_ok = (n_in == 19)
        && in_sizes[0] == 30000 * 25
        && in_sizes[1] == 480000 * 14
        && in_sizes[4] == 270 * 256
        && in_sizes[10] == 512 * 1024
        && in_sizes[17] == 2 * 480000
        && in_sizes[18] == 30000;
    if (!sizes_ok) { fillv_kernel<<<2, 256, 0, stream>>>(d_out, flag, 1600.0f); return; }
    if (ws_size < (size_t)WS_NEEDED) { fillv_kernel<<<2, 256, 0, stream>>>(d_out, flag, 800.0f); return; }
    const int fastlvl = (ws_size >= (size_t)WS_FAST2) ? 2
                      : (ws_size >= (size_t)WS_FAST)  ? 1 : 0;

    fillv_kernel<<<2, 256, 0, stream>>>(d_out, flag, 3.0f);
    DMPNN_Change_678604832935_kernel<<<1, 64, 0, stream>>>((int*)(ws + OFF_G));

    const void* x     = d_in[0];
    const void* eattr = d_in[1];
    const void* W0    = d_in[2];
    const void* b0    = d_in[3];
    const void* Wm1   = d_in[4];
    const void* bm1   = d_in[5];
    const void* Wm2   = d_in[6];
    const void* bm2   = d_in[7];
    const void* Wr    = d_in[8];
    const void* br    = d_in[9];
    const void* Wih   = d_in[10];
    const void* Whh   = d_in[11];
    const void* bl    = d_in[12];
    const void* W1    = d_in[13];
    const void* b1    = d_in[14];
    const void* W2    = d_in[15];
    const void* b2    = d_in[16];
    const int* eidx   = (const int*)d_in[17];
    const int* batch  = (const int*)d_in[18];

    // all weight relayouts in one launch
    to_blocked_all<<<3872, 256, 0, stream>>>(Wm1, Wm2, Wr, Wih, Whh, flag,
                                             Wm1b, Wm2b, Wrb, Wcatb);

    if (fastlvl >= 1) {
        // fused lin0 + qgen (needs Wm1b + Qb space)
        lin0q_kernel<<<469, 256, 0, stream>>>(x, W0, b0, flag, Wm1b, h0b, Qb);
    } else {
        lin0_kernel<<<3750, 256, 0, stream>>>(x, W0, b0, flag, h0b);
    }

    // counting sort of edges by dst (CSR); integer atomics only
    zero_kernel<<<30, 256, 0, stream>>>((float*)cursor, 30000);
    hist_kernel<<<1875, 256, 0, stream>>>(eidx, cursor);
    scan1_kernel<<<118, 256, 0, stream>>>(cursor, part);
    scan2_kernel<<<1, 128, 0, stream>>>(part, pexcl, 118);
    scan3_kernel<<<118, 256, 0, stream>>>(cursor, pexcl);
    scatter_kernel<<<1875, 256, 0, stream>>>(eidx, cursor, permLo, permHi,
                                             (fastlvl == 2) ? srcW : (u16*)nullptr);

    int agg_bf16 = 0;
    if (fastlvl == 2) {
        agg_bf16 = 1;
        edge_mfma_node2_kernel<<<30000, 256, 0, stream>>>(Qb, eattr, srcW, permLo, permHi,
                                                          cursor, Wm1b, bm1, flag,
                                                          (u16*)aggP);
    } else if (fastlvl == 1) {
        edge_mfma_node_kernel<<<30000, 256, 0, stream>>>(Qb, eattr, eidx, permLo, permHi,
                                                         cursor, Wm1b, bm1, flag, aggP);
    } else {
        zero_kernel<<<1024, 256, 0, stream>>>(aggP, 7680000);
        edge_sorted_kernel<<<7500, 256, 0, stream>>>(h0b, eattr, eidx, permLo, permHi,
                                                     Wm1b, bm1, flag, aggP);
    }
    node_dual_kernel<<<469, 256, 0, stream>>>(h0b, Wrb, Wm2b, br, bm2,
                                              aggP, agg_bf16, cursor, flag);

    // zero Cst + Abuf AFTER node_dual: Abuf aliases the aggP region (invariant above)
    zero2_kernel<<<256, 256, 0, stream>>>(Cst, 131072, (float*)Abuf, 196608);

    for (int s = 0; s < 3; ++s) {
        gates_mfma_kernel<<<dim3(8, 16), 256, 0, stream>>>(Abuf, Wcatb, G);
        s2s_lstm_fused_kernel<<<512, 256, 0, stream>>>(G, bl, flag, Cst, Hst,
                                                       h0b, batch, Rst, Abuf, ebuf);
    }
    readout_kernel<<<512, 256, 0, stream>>>(Hst, Rst, W1, b1, W2, b2, h0b,
                                            aggP, agg_bf16, flag, d_out);
}

// Round 10
// 454.032 us; speedup vs baseline: 1.1882x; 1.0515x over previous
//
#include <hip/hip_runtime.h>

typedef unsigned short u16;
typedef unsigned char u8;
typedef unsigned int u32;
using s16x8 = __attribute__((ext_vector_type(8))) short;
using s16x4 = __attribute__((ext_vector_type(4))) short;
using f32x4 = __attribute__((ext_vector_type(4))) float;

#define DEV static __device__ __forceinline__

DEV float b2f(u16 u) { return __uint_as_float(((u32)u) << 16); }
DEV u16 f2bu(float f) {               // f32 -> bf16 bits, round-to-nearest-even
    u32 u = __float_as_uint(f);
    u32 r = (u + 0x7FFFu + ((u >> 16) & 1u)) >> 16;
    return (u16)r;
}
DEV float sigm(float x) { return 1.0f / (1.0f + expf(-x)); }

DEV float ldv(const void* p, int i, int f32flag) {
    if (f32flag) return ((const float*)p)[i];
    return b2f(((const u16*)p)[i]);
}
DEV void stv(void* p, int i, float v, int f32flag) {
    if (f32flag) ((float*)p)[i] = v;
    else ((u16*)p)[i] = f2bu(v);
}

DEV int lower_bound(const int* b, int n, int v) {
    int lo = 0, hi = n;
    while (lo < hi) { int mid = (lo + hi) >> 1; if (b[mid] < v) lo = mid + 1; else hi = mid; }
    return lo;
}

// identifier-named kernel from the stub skeleton (kept; harmless)
__global__ void DMPNN_Change_678604832935_kernel(int* p) {
    if (p && threadIdx.x == 0 && blockIdx.x == 0) p[0] = 1;
}

// ---- dtype sniffer ----
__global__ void detect_kernel(const void* x, int* flag) {
    __shared__ int cnt[128];
    int tid = threadIdx.x;
    if (tid < 128) {
        u16 v = ((const u16*)x)[tid];
        int e = (v >> 7) & 0xFF;
        cnt[tid] = (e >= 100 && e <= 141) ? 1 : 0;
    }
    __syncthreads();
    if (tid == 0) {
        int s = 0;
        for (int i = 0; i < 128; ++i) s += cnt[i];
        flag[0] = (s < 110) ? 1 : 0;   // 1 = float32 data, 0 = bf16 data
    }
}

__global__ void fillv_kernel(void* out, const int* flag, float v) {
    int i = blockIdx.x * 256 + threadIdx.x;
    if (i < 512) stv(out, i, v, flag[0]);
}

__global__ void zero_kernel(float* p, int n) {
    int i = blockIdx.x * 256 + threadIdx.x;
    int stride = gridDim.x * 256;
    for (; i < n; i += stride) p[i] = 0.0f;
}

// one launch zeroing two regions (Cst, Abuf) — runs AFTER node_dual because
// Abuf aliases the aggP region (workspace reuse); see layout invariant below.
__global__ void zero2_kernel(float* a, int na, float* b, int nb) {
    int i = blockIdx.x * 256 + threadIdx.x;
    int stride = gridDim.x * 256;
    for (int j = i; j < na; j += stride) a[j] = 0.0f;
    for (int j = i; j < nb; j += stride) b[j] = 0.0f;
}

// ---- counting sort of edges by dst: histogram -> scan -> scatter ----
// (integer atomics only: counts/positions are order-invariant; the permutation
//  order within a segment is canonicalized later by the rank sort)
__global__ void hist_kernel(const int* __restrict__ eidx, u32* __restrict__ cnt) {
    int i = blockIdx.x * 256 + threadIdx.x;
    if (i < 480000) atomicAdd(&cnt[eidx[480000 + i]], 1u);
}

__global__ void scan1_kernel(const u32* __restrict__ cnt, u32* __restrict__ part) {
    __shared__ u32 s[256];
    int i = blockIdx.x * 256 + threadIdx.x;
    s[threadIdx.x] = (i < 30000) ? cnt[i] : 0u;
    __syncthreads();
    for (int st = 128; st > 0; st >>= 1) {
        if (threadIdx.x < st) s[threadIdx.x] += s[threadIdx.x + st];
        __syncthreads();
    }
    if (threadIdx.x == 0) part[blockIdx.x] = s[0];
}

// wave-parallel exclusive scan of <=128 partials
__global__ void scan2_kernel(const u32* __restrict__ part, u32* __restrict__ pexcl, int nb) {
    int tid = threadIdx.x;              // blockDim = 128
    u32 v = (tid < nb) ? part[tid] : 0u;
    u32 x = v;
    #pragma unroll
    for (int off = 1; off < 64; off <<= 1) {
        u32 t = __shfl_up(x, off, 64);
        if ((tid & 63) >= off) x += t;
    }
    __shared__ u32 wsum;
    if (tid == 63) wsum = x;
    __syncthreads();
    u32 add = (tid >= 64) ? wsum : 0u;
    if (tid < nb) pexcl[tid] = x + add - v;   // exclusive
}

__global__ void scan3_kernel(u32* __restrict__ cursor, const u32* __restrict__ pexcl) {
    __shared__ u32 s[256];
    int b = blockIdx.x, tid = threadIdx.x;
    int i = b * 256 + tid;
    u32 v = (i < 30000) ? cursor[i] : 0u;
    s[tid] = v;
    __syncthreads();
    for (int off = 1; off < 256; off <<= 1) {
        u32 t = (tid >= off) ? s[tid - off] : 0u;
        __syncthreads();
        s[tid] += t;
        __syncthreads();
    }
    u32 excl = s[tid] - v + pexcl[b];
    if (i < 30000) cursor[i] = excl;
}

// scatter; optionally also records the edge's SRC (u16) at the sorted position,
// removing one dependent gather level from the edge kernel (srcW may be null).
__global__ void scatter_kernel(const int* __restrict__ eidx, u32* __restrict__ cursor,
                               u16* __restrict__ permLo, u8* __restrict__ permHi,
                               u16* __restrict__ srcW) {
    int i = blockIdx.x * 256 + threadIdx.x;
    if (i < 480000) {
        int d = eidx[480000 + i];
        u32 pos = atomicAdd(&cursor[d], 1u);
        permLo[pos] = (u16)(i & 0xFFFF);
        permHi[pos] = (u8)(i >> 16);
        if (srcW) srcW[pos] = (u16)eidx[i];
    }
}

// ---- ALL weights -> k-tile-blocked bf16 layouts in ONE launch ----
// regions: Wm1 (ktiles=9,N=256) | Wm2 (8,256) | Wr (8,256) | Wcat (24,N=1024)
__global__ void to_blocked_all(const void* Wm1, const void* Wm2, const void* Wr,
                               const void* Wih, const void* Whh, const int* flag,
                               u16* Wm1b, u16* Wm2b, u16* Wrb, u16* Wcatb) {
    const int T1 = 9 * 4 * 256 * 8;            // 73728
    const int T2 = T1 + 8 * 4 * 256 * 8;       // +65536
    const int T3 = T2 + 8 * 4 * 256 * 8;       // +65536
    const int T4 = T3 + 24 * 4 * 1024 * 8;     // +786432
    int idx = blockIdx.x * 256 + threadIdx.x;
    if (idx >= T4) return;
    int f32 = flag[0];
    if (idx < T3) {
        const void* src; u16* dst; int K; int l;
        if (idx < T1)      { src = Wm1; dst = Wm1b; K = 270; l = idx; }
        else if (idx < T2) { src = Wm2; dst = Wm2b; K = 256; l = idx - T1; }
        else               { src = Wr;  dst = Wrb;  K = 256; l = idx - T2; }
        int c = l & 7;
        int n = (l >> 3) & 255;
        int jk = l >> 11;
        int j = jk & 3, kt = jk >> 2;
        int k = kt * 32 + j * 8 + c;
        u16 v = 0;
        if (k < K) v = f2bu(ldv(src, k * 256 + n, f32));
        dst[l] = v;
    } else {
        int l = idx - T3;
        int c = l & 7;
        int n = (l >> 3) & 1023;
        int jk = l >> 13;
        int j = jk & 3, kt = jk >> 2;
        int k = kt * 32 + j * 8 + c;
        u16 v = 0;
        if (k < 512) v = f2bu(ldv(Wih, k * 1024 + n, f32));
        else if (k < 768) v = f2bu(ldv(Whh, (k - 512) * 1024 + n, f32));
        Wcatb[l] = v;
    }
}

// ---- lin0 (fallback path only): h0 = relu(x @ W0 + b0), 8 nodes/block ----
__global__ __launch_bounds__(256) void lin0_kernel(const void* x, const void* W0,
                                                   const void* b0, const int* flag,
                                                   u16* h0b) {
    int f32 = flag[0];
    int n0 = blockIdx.x * 8, tid = threadIdx.x;
    __shared__ float xs[8][26];
    if (tid < 200) {
        int nn = tid / 25, k = tid % 25;
        xs[nn][k] = ldv(x, (n0 + nn) * 25 + k, f32);
    }
    __syncthreads();
    float wr[25];
    #pragma unroll
    for (int k = 0; k < 25; ++k) wr[k] = ldv(W0, k * 256 + tid, f32);
    float bias = ldv(b0, tid, f32);
    #pragma unroll
    for (int nn = 0; nn < 8; ++nn) {
        float a = bias;
        #pragma unroll
        for (int k = 0; k < 25; ++k) a += xs[nn][k] * wr[k];
        h0b[(n0 + nn) * 256 + tid] = f2bu(fmaxf(a, 0.0f));
    }
}

// ---- FUSED lin0 + qgen: compute h0 tile (64 rows, VALU, K=25) into LDS,
// write h0b, then Q = h0 @ Wm1top via MFMA from the SAME LDS tile. ----
__global__ __launch_bounds__(256) void lin0q_kernel(
    const void* x, const void* W0, const void* b0, const int* flag,
    const u16* __restrict__ Wm1b, u16* __restrict__ h0b, u16* __restrict__ Qb) {
    __shared__ __attribute__((aligned(16))) u16 As[64 * 264];
    __shared__ float xs[64][26];
    const int f32 = flag[0];
    const int tid = threadIdx.x;
    const int w = tid >> 6, lane = tid & 63, quad = lane >> 4, mrow = lane & 15;
    const int row0 = blockIdx.x * 64;
    const int colb = w * 64 + mrow;

    for (int idx = tid; idx < 64 * 25; idx += 256) {
        int i = idx / 25, k = idx - i * 25;
        int row = row0 + i;
        xs[i][k] = (row < 30000) ? ldv(x, row * 25 + k, f32) : 0.0f;
    }
    float wr[25];
    #pragma unroll
    for (int k = 0; k < 25; ++k) wr[k] = ldv(W0, k * 256 + tid, f32);
    float bias = ldv(b0, tid, f32);
    __syncthreads();
    for (int i = 0; i < 64; ++i) {
        float a = bias;
        #pragma unroll
        for (int k = 0; k < 25; ++k) a += xs[i][k] * wr[k];
        u16 hb = f2bu(fmaxf(a, 0.0f));
        As[i * 264 + tid] = hb;        // out-of-range rows hold relu(bias); their
        int row = row0 + i;            // MFMA results are discarded by the C-guard
        if (row < 30000) h0b[row * 256 + tid] = hb;
    }
    __syncthreads();

    f32x4 acc[4][4];
    f32x4 fzero = {0.f, 0.f, 0.f, 0.f};
    #pragma unroll
    for (int mi = 0; mi < 4; ++mi)
        #pragma unroll
        for (int ni = 0; ni < 4; ++ni) acc[mi][ni] = fzero;

    for (int kt = 0; kt < 8; ++kt) {
        s16x8 af[4], bf[4];
        #pragma unroll
        for (int ni = 0; ni < 4; ++ni)
            bf[ni] = *(const s16x8*)(Wm1b + (((kt * 4 + quad) * 256) + colb + ni * 16) * 8);
        #pragma unroll
        for (int mi = 0; mi < 4; ++mi)
            af[mi] = *(const s16x8*)(As + (mi * 16 + mrow) * 264 + kt * 32 + quad * 8);
        #pragma unroll
        for (int mi = 0; mi < 4; ++mi)
            #pragma unroll
            for (int ni = 0; ni < 4; ++ni)
                acc[mi][ni] = __builtin_amdgcn_mfma_f32_16x16x32_bf16(af[mi], bf[ni], acc[mi][ni], 0, 0, 0);
    }

    #pragma unroll
    for (int mi = 0; mi < 4; ++mi)
        #pragma unroll
        for (int rg = 0; rg < 4; ++rg) {
            int row = row0 + mi * 16 + quad * 4 + rg;
            if (row >= 30000) continue;
            #pragma unroll
            for (int ni = 0; ni < 4; ++ni)
                Qb[row * 256 + colb + ni * 16] = f2bu(acc[mi][ni][rg]);
        }
}

// ---- Q = h0 @ Wm1top (kept for fastlvl==1 path) ----
__global__ __launch_bounds__(256) void qgen_kernel(
    const u16* __restrict__ h0b, const u16* __restrict__ Wm1b,
    u16* __restrict__ Qb) {
    __shared__ __attribute__((aligned(16))) u16 As[64 * 264];
    const int tid = threadIdx.x;
    const int w = tid >> 6, lane = tid & 63, quad = lane >> 4, mrow = lane & 15;
    const int row0 = blockIdx.x * 64;
    const int colb = w * 64 + mrow;
    const int r = tid >> 2, sub = tid & 3;

    {
        int row = row0 + r;
        u16* arow = As + r * 264;
        #pragma unroll
        for (int j = 0; j < 8; ++j) {
            int c0 = sub * 64 + j * 8;
            s16x8 v = {0, 0, 0, 0, 0, 0, 0, 0};
            if (row < 30000) v = *(const s16x8*)(h0b + row * 256 + c0);
            *(s16x8*)(arow + c0) = v;
        }
    }
    __syncthreads();

    f32x4 acc[4][4];
    f32x4 fzero = {0.f, 0.f, 0.f, 0.f};
    #pragma unroll
    for (int mi = 0; mi < 4; ++mi)
        #pragma unroll
        for (int ni = 0; ni < 4; ++ni) acc[mi][ni] = fzero;

    for (int kt = 0; kt < 8; ++kt) {
        s16x8 af[4], bf[4];
        #pragma unroll
        for (int ni = 0; ni < 4; ++ni)
            bf[ni] = *(const s16x8*)(Wm1b + (((kt * 4 + quad) * 256) + colb + ni * 16) * 8);
        #pragma unroll
        for (int mi = 0; mi < 4; ++mi)
            af[mi] = *(const s16x8*)(As + (mi * 16 + mrow) * 264 + kt * 32 + quad * 8);
        #pragma unroll
        for (int mi = 0; mi < 4; ++mi)
            #pragma unroll
            for (int ni = 0; ni < 4; ++ni)
                acc[mi][ni] = __builtin_amdgcn_mfma_f32_16x16x32_bf16(af[mi], bf[ni], acc[mi][ni], 0, 0, 0);
    }

    #pragma unroll
    for (int mi = 0; mi < 4; ++mi)
        #pragma unroll
        for (int rg = 0; rg < 4; ++rg) {
            int row = row0 + mi * 16 + quad * 4 + rg;
            if (row >= 30000) continue;
            #pragma unroll
            for (int ni = 0; ni < 4; ++ni)
                Qb[row * 256 + colb + ni * 16] = f2bu(acc[mi][ni][rg]);
        }
}

// ---- edge aggregation v2 (fastlvl 2) ----
#define MAXD 96
__global__ __launch_bounds__(256) void edge_mfma_node2_kernel(
    const u16* __restrict__ Qb, const void* __restrict__ eattr,
    const u16* __restrict__ srcW,
    const u16* __restrict__ permLo, const u8* __restrict__ permHi,
    const u32* __restrict__ cursor,
    const u16* __restrict__ Wm1b, const void* __restrict__ bm1,
    const int* __restrict__ flag, u16* __restrict__ aggB) {
    const int f32 = flag[0];
    const int n = blockIdx.x, tid = threadIdx.x;
    const int w = tid >> 6, lane = tid & 63, quad = lane >> 4, mrow = lane & 15;
    const int beg = (n > 0) ? (int)cursor[n - 1] : 0;
    const int end = (int)cursor[n];
    __shared__ int eids[MAXD];
    __shared__ int srcl[MAXD];
    __shared__ int sorted_s[MAXD];
    __shared__ int sortedSrc[MAXD];
    __shared__ __attribute__((aligned(16))) u16 Ae[16 * 40];   // 16 edges x K=32 (+pad)

    const int colb = w * 64 + mrow;
    s16x8 bf[4];
    float bm1c[4];
    #pragma unroll
    for (int ni = 0; ni < 4; ++ni) {
        bf[ni] = *(const s16x8*)(Wm1b + (((32 + quad) * 256) + colb + ni * 16) * 8);
        bm1c[ni] = ldv(bm1, colb + ni * 16, f32);
    }

    float psum[4] = {0.f, 0.f, 0.f, 0.f};
    const f32x4 fzero = {0.f, 0.f, 0.f, 0.f};

    for (int base = beg; base < end; base += MAXD) {
        int wcnt = end - base; if (wcnt > MAXD) wcnt = MAXD;
        if (tid < wcnt) {
            int si = base + tid;
            eids[tid] = (int)permLo[si] | ((int)permHi[si] << 16);
            srcl[tid] = (int)srcW[si];
        }
        __syncthreads();
        if (tid < wcnt) {   // canonical rank sort; carry src alongside the key
            int key = eids[tid], r2 = 0;
            for (int j = 0; j < wcnt; ++j) r2 += (eids[j] < key);
            sorted_s[r2] = key;
            sortedSrc[r2] = srcl[tid];
        }
        __syncthreads();

        for (int cb = 0; cb < wcnt; cb += 16) {
            // stage a 16-edge chunk of eattr (bf16, zero-padded to K=32)
            {
                int row = tid >> 4, c = tid & 15;
                int gi = cb + row;
                int e = (gi < wcnt) ? sorted_s[gi] : -1;
                u16 v = 0;
                if (e >= 0 && c < 14) v = f2bu(ldv(eattr, e * 14 + c, f32));
                Ae[row * 40 + c] = v;
                Ae[row * 40 + 16 + c] = 0;
            }
            __syncthreads();

            // prefetch Q values for this quad's rows (independent of the MFMA)
            float qv[4][4];
            #pragma unroll
            for (int rg = 0; rg < 4; ++rg) {
                int gi = cb + quad * 4 + rg;
                int sidx = (gi < wcnt) ? sortedSrc[gi] : 0;
                const u16* qrow = Qb + sidx * 256;
                #pragma unroll
                for (int ni = 0; ni < 4; ++ni)
                    qv[rg][ni] = b2f(qrow[colb + ni * 16]);
            }

            s16x8 af = *(const s16x8*)(Ae + mrow * 40 + quad * 8);
            f32x4 acc[4];
            #pragma unroll
            for (int ni = 0; ni < 4; ++ni)
                acc[ni] = __builtin_amdgcn_mfma_f32_16x16x32_bf16(af, bf[ni], fzero, 0, 0, 0);

            #pragma unroll
            for (int rg = 0; rg < 4; ++rg) {
                if (cb + quad * 4 + rg < wcnt) {
                    #pragma unroll
                    for (int ni = 0; ni < 4; ++ni)
                        psum[ni] += fmaxf(acc[ni][rg] + bm1c[ni] + qv[rg][ni], 0.0f);
                }
            }
            __syncthreads();   // protect Ae before next chunk restage
        }
    }

    #pragma unroll
    for (int ni = 0; ni < 4; ++ni) {
        float v = psum[ni];
        v += __shfl_xor(v, 16, 64);
        v += __shfl_xor(v, 32, 64);
        psum[ni] = v;
    }
    if (quad == 0) {
        #pragma unroll
        for (int ni = 0; ni < 4; ++ni)
            aggB[n * 256 + colb + ni * 16] = f2bu(psum[ni]);
    }
}

// ---- edge aggregation v1 (fastlvl 1, round-4 proven): f32 aggP ----
__global__ __launch_bounds__(256) void edge_mfma_node_kernel(
    const u16* __restrict__ Qb, const void* __restrict__ eattr,
    const int* __restrict__ eidx,
    const u16* __restrict__ permLo, const u8* __restrict__ permHi,
    const u32* __restrict__ cursor,
    const u16* __restrict__ Wm1b, const void* __restrict__ bm1,
    const int* __restrict__ flag, float* __restrict__ aggP) {
    const int f32 = flag[0];
    const int n = blockIdx.x, tid = threadIdx.x;
    const int w = tid >> 6, lane = tid & 63, quad = lane >> 4, mrow = lane & 15;
    const int beg = (n > 0) ? (int)cursor[n - 1] : 0;
    const int end = (int)cursor[n];
    __shared__ int eids[MAXD];
    __shared__ int sorted_s[MAXD];
    __shared__ int srcs16[16];
    __shared__ __attribute__((aligned(16))) u16 Ae[16 * 40];

    const int colb = w * 64 + mrow;
    s16x8 bf[4];
    float bm1c[4];
    #pragma unroll
    for (int ni = 0; ni < 4; ++ni) {
        bf[ni] = *(const s16x8*)(Wm1b + (((32 + quad) * 256) + colb + ni * 16) * 8);
        bm1c[ni] = ldv(bm1, colb + ni * 16, f32);
    }

    float psum[4] = {0.f, 0.f, 0.f, 0.f};
    const f32x4 fzero = {0.f, 0.f, 0.f, 0.f};

    for (int base = beg; base < end; base += MAXD) {
        int wcnt = end - base; if (wcnt > MAXD) wcnt = MAXD;
        if (tid < wcnt) {
            int si = base + tid;
            eids[tid] = (int)permLo[si] | ((int)permHi[si] << 16);
        }
        __syncthreads();
        if (tid < wcnt) {
            int key = eids[tid], r2 = 0;
            for (int j = 0; j < wcnt; ++j) r2 += (eids[j] < key);
            sorted_s[r2] = key;
        }
        __syncthreads();

        for (int cb = 0; cb < wcnt; cb += 16) {
            {
                int row = tid >> 4, c = tid & 15;
                int gi = cb + row;
                int e = (gi < wcnt) ? sorted_s[gi] : -1;
                u16 v = 0;
                if (e >= 0 && c < 14) v = f2bu(ldv(eattr, e * 14 + c, f32));
                Ae[row * 40 + c] = v;
                Ae[row * 40 + 16 + c] = 0;
                if (c == 0) srcs16[row] = (e >= 0) ? eidx[e] : 0;
            }
            __syncthreads();

            s16x8 af = *(const s16x8*)(Ae + mrow * 40 + quad * 8);
            f32x4 acc[4];
            #pragma unroll
            for (int ni = 0; ni < 4; ++ni)
                acc[ni] = __builtin_amdgcn_mfma_f32_16x16x32_bf16(af, bf[ni], fzero, 0, 0, 0);

            #pragma unroll
            for (int rg = 0; rg < 4; ++rg) {
                int row = quad * 4 + rg;
                if (cb + row < wcnt) {
                    const u16* qrow = Qb + srcs16[row] * 256;
                    #pragma unroll
                    for (int ni = 0; ni < 4; ++ni) {
                        float q = b2f(qrow[colb + ni * 16]);
                        psum[ni] += fmaxf(acc[ni][rg] + bm1c[ni] + q, 0.0f);
                    }
                }
            }
            __syncthreads();
        }
    }

    #pragma unroll
    for (int ni = 0; ni < 4; ++ni) {
        float v = psum[ni];
        v += __shfl_xor(v, 16, 64);
        v += __shfl_xor(v, 32, 64);
        psum[ni] = v;
    }
    if (quad == 0) {
        #pragma unroll
        for (int ni = 0; ni < 4; ++ni)
            aggP[n * 256 + colb + ni * 16] = psum[ni];
    }
}

// ---- FALLBACK edge kernel: GEMM1 in-kernel, atomic f32 aggP ----
__global__ __launch_bounds__(256) void edge_sorted_kernel(
    const u16* __restrict__ h0b, const void* __restrict__ eattr,
    const int* __restrict__ eidx,
    const u16* __restrict__ permLo, const u8* __restrict__ permHi,
    const u16* __restrict__ Wm1b,
    const void* __restrict__ bm1,
    const int* __restrict__ flag, float* __restrict__ aggP) {
    __shared__ __attribute__((aligned(16))) u16 As[64 * 296];
    __shared__ int dsh[64];
    const int f32 = flag[0];
    const int tid = threadIdx.x;
    const int w = tid >> 6, lane = tid & 63, quad = lane >> 4, mrow = lane & 15;
    const int eb0 = blockIdx.x * 64;
    const int colb = w * 64 + mrow;

    if (tid < 64) {
        int sj = eb0 + tid;
        int ee = (int)permLo[sj] | ((int)permHi[sj] << 16);
        dsh[tid] = eidx[480000 + ee];
    }
    {
        int r = tid >> 2, sub = tid & 3;
        int si = eb0 + r;
        int e = (int)permLo[si] | ((int)permHi[si] << 16);
        int src = eidx[e];
        const u16* hrow = h0b + src * 256;
        u16* arow = As + r * 296;
        #pragma unroll
        for (int j = 0; j < 8; ++j) {
            int c0 = sub * 64 + j * 8;
            *(s16x8*)(arow + c0) = *(const s16x8*)(hrow + c0);
        }
        if (sub == 0) {
            for (int c = 0; c < 14; ++c) arow[256 + c] = f2bu(ldv(eattr, e * 14 + c, f32));
            for (int c = 14; c < 40; ++c) arow[256 + c] = 0;
        }
    }
    __syncthreads();

    f32x4 acc[4][4];
    f32x4 fzero = {0.f, 0.f, 0.f, 0.f};
    #pragma unroll
    for (int mi = 0; mi < 4; ++mi)
        #pragma unroll
        for (int ni = 0; ni < 4; ++ni) acc[mi][ni] = fzero;

    for (int kt = 0; kt < 9; ++kt) {
        s16x8 af[4], bf[4];
        #pragma unroll
        for (int ni = 0; ni < 4; ++ni)
            bf[ni] = *(const s16x8*)(Wm1b + (((kt * 4 + quad) * 256) + colb + ni * 16) * 8);
        #pragma unroll
        for (int mi = 0; mi < 4; ++mi)
            af[mi] = *(const s16x8*)(As + (mi * 16 + mrow) * 296 + kt * 32 + quad * 8);
        #pragma unroll
        for (int mi = 0; mi < 4; ++mi)
            #pragma unroll
            for (int ni = 0; ni < 4; ++ni)
                acc[mi][ni] = __builtin_amdgcn_mfma_f32_16x16x32_bf16(af[mi], bf[ni], acc[mi][ni], 0, 0, 0);
    }

    float bm1c[4];
    #pragma unroll
    for (int ni = 0; ni < 4; ++ni) bm1c[ni] = ldv(bm1, colb + ni * 16, f32);
    __syncthreads();
    #pragma unroll
    for (int mi = 0; mi < 4; ++mi)
        #pragma unroll
        for (int ni = 0; ni < 4; ++ni)
            #pragma unroll
            for (int rg = 0; rg < 4; ++rg) {
                int row = mi * 16 + quad * 4 + rg;
                As[row * 296 + colb + ni * 16] = f2bu(fmaxf(acc[mi][ni][rg] + bm1c[ni], 0.0f));
            }
    __syncthreads();

    {
        int c = tid;
        float s = 0.0f;
        int cur = dsh[0];
        #pragma unroll 8
        for (int rr = 0; rr < 64; ++rr) {
            int d = dsh[rr];
            if (d != cur) { atomicAdd(&aggP[cur * 256 + c], s); s = 0.0f; cur = d; }
            s += b2f(As[rr * 296 + c]);
        }
        atomicAdd(&aggP[cur * 256 + c], s);
    }
}

// ---- fused node update: out = relu(h0@Wr + agg@Wm2 + br + deg*bm2), in-place bf16.
// agg may be bf16 (fast2) or f32 (other paths); deg computed from cursor. ----
__global__ __launch_bounds__(256) void node_dual_kernel(
    u16* __restrict__ h0b, const u16* __restrict__ Wrb, const u16* __restrict__ Wm2b,
    const void* __restrict__ br, const void* __restrict__ bm2,
    const void* __restrict__ aggV, int agg_bf16,
    const u32* __restrict__ cursor,
    const int* __restrict__ flag) {
    __shared__ __attribute__((aligned(16))) u16 As[64 * 264];
    const int f32 = flag[0];
    const int tid = threadIdx.x;
    const int w = tid >> 6, lane = tid & 63, quad = lane >> 4, mrow = lane & 15;
    const int row0 = blockIdx.x * 64;
    const int colb = w * 64 + mrow;
    const int r = tid >> 2, sub = tid & 3;

    {
        int row = row0 + r;
        u16* arow = As + r * 264;
        #pragma unroll
        for (int j = 0; j < 8; ++j) {
            int c0 = sub * 64 + j * 8;
            s16x8 v = {0, 0, 0, 0, 0, 0, 0, 0};
            if (row < 30000) v = *(const s16x8*)(h0b + row * 256 + c0);
            *(s16x8*)(arow + c0) = v;
        }
    }
    __syncthreads();

    f32x4 acc[4][4];
    f32x4 fzero = {0.f, 0.f, 0.f, 0.f};
    #pragma unroll
    for (int mi = 0; mi < 4; ++mi)
        #pragma unroll
        for (int ni = 0; ni < 4; ++ni) acc[mi][ni] = fzero;

    for (int kt = 0; kt < 8; ++kt) {
        s16x8 af[4], bf[4];
        #pragma unroll
        for (int ni = 0; ni < 4; ++ni)
            bf[ni] = *(const s16x8*)(Wrb + (((kt * 4 + quad) * 256) + colb + ni * 16) * 8);
        #pragma unroll
        for (int mi = 0; mi < 4; ++mi)
            af[mi] = *(const s16x8*)(As + (mi * 16 + mrow) * 264 + kt * 32 + quad * 8);
        #pragma unroll
        for (int mi = 0; mi < 4; ++mi)
            #pragma unroll
            for (int ni = 0; ni < 4; ++ni)
                acc[mi][ni] = __builtin_amdgcn_mfma_f32_16x16x32_bf16(af[mi], bf[ni], acc[mi][ni], 0, 0, 0);
    }
    __syncthreads();

    // restage agg rows into As (bf16)
    {
        int row = row0 + r;
        u16* arow = As + r * 264;
        if (agg_bf16) {
            const u16* aggB = (const u16*)aggV;
            #pragma unroll
            for (int j = 0; j < 8; ++j) {
                int c0 = sub * 64 + j * 8;
                s16x8 v = {0, 0, 0, 0, 0, 0, 0, 0};
                if (row < 30000) v = *(const s16x8*)(aggB + row * 256 + c0);
                *(s16x8*)(arow + c0) = v;
            }
        } else {
            const float* aggP = (const float*)aggV;
            #pragma unroll
            for (int j = 0; j < 8; ++j) {
                int c0 = sub * 64 + j * 8;
                s16x8 pk = {0, 0, 0, 0, 0, 0, 0, 0};
                if (row < 30000) {
                    f32x4 a = *(const f32x4*)(aggP + row * 256 + c0);
                    f32x4 b = *(const f32x4*)(aggP + row * 256 + c0 + 4);
                    pk[0] = (short)f2bu(a[0]); pk[1] = (short)f2bu(a[1]);
                    pk[2] = (short)f2bu(a[2]); pk[3] = (short)f2bu(a[3]);
                    pk[4] = (short)f2bu(b[0]); pk[5] = (short)f2bu(b[1]);
                    pk[6] = (short)f2bu(b[2]); pk[7] = (short)f2bu(b[3]);
                }
                *(s16x8*)(arow + c0) = pk;
            }
        }
    }
    __syncthreads();

    for (int kt = 0; kt < 8; ++kt) {
        s16x8 af[4], bf[4];
        #pragma unroll
        for (int ni = 0; ni < 4; ++ni)
            bf[ni] = *(const s16x8*)(Wm2b + (((kt * 4 + quad) * 256) + colb + ni * 16) * 8);
        #pragma unroll
        for (int mi = 0; mi < 4; ++mi)
            af[mi] = *(const s16x8*)(As + (mi * 16 + mrow) * 264 + kt * 32 + quad * 8);
        #pragma unroll
        for (int mi = 0; mi < 4; ++mi)
            #pragma unroll
            for (int ni = 0; ni < 4; ++ni)
                acc[mi][ni] = __builtin_amdgcn_mfma_f32_16x16x32_bf16(af[mi], bf[ni], acc[mi][ni], 0, 0, 0);
    }

    #pragma unroll
    for (int mi = 0; mi < 4; ++mi)
        #pragma unroll
        for (int rg = 0; rg < 4; ++rg) {
            int row = row0 + mi * 16 + quad * 4 + rg;
            if (row >= 30000) continue;
            float dg = (float)(cursor[row] - (row > 0 ? cursor[row - 1] : 0u));
            #pragma unroll
            for (int ni = 0; ni < 4; ++ni) {
                int col = colb + ni * 16;
                float v = acc[mi][ni][rg] + ldv(br, col, f32) + dg * ldv(bm2, col, f32);
                h0b[row * 256 + col] = f2bu(fmaxf(v, 0.0f));
            }
        }
}

// ---- Set2Set gates via MFMA: 128 blocks (64x64 tiles, wave = 16 cols) ----
__global__ __launch_bounds__(256) void gates_mfma_kernel(
    const u16* __restrict__ Abuf, const u16* __restrict__ Wcatb,
    float* __restrict__ G) {
    const int tid = threadIdx.x;
    const int w = tid >> 6, lane = tid & 63, quad = lane >> 4, mrow = lane & 15;
    const int row0 = blockIdx.x * 64;
    const int col = blockIdx.y * 64 + w * 16 + mrow;

    f32x4 acc[4];
    f32x4 fzero = {0.f, 0.f, 0.f, 0.f};
    #pragma unroll
    for (int mi = 0; mi < 4; ++mi) acc[mi] = fzero;

    for (int kt = 0; kt < 24; ++kt) {
        s16x8 bfv = *(const s16x8*)(Wcatb + (((kt * 4 + quad) * 1024) + col) * 8);
        s16x8 af[4];
        #pragma unroll
        for (int mi = 0; mi < 4; ++mi)
            af[mi] = *(const s16x8*)(Abuf + (row0 + mi * 16 + mrow) * 768 + kt * 32 + quad * 8);
        #pragma unroll
        for (int mi = 0; mi < 4; ++mi)
            acc[mi] = __builtin_amdgcn_mfma_f32_16x16x32_bf16(af[mi], bfv, acc[mi], 0, 0, 0);
    }

    #pragma unroll
    for (int mi = 0; mi < 4; ++mi)
        #pragma unroll
        for (int rg = 0; rg < 4; ++rg)
            G[(row0 + mi * 16 + quad * 4 + rg) * 1024 + col] = acc[mi][rg];
}

// ---- fused LSTM + Set2Set attention ----
#define GROWS 112
__global__ __launch_bounds__(256) void s2s_lstm_fused_kernel(
    const float* __restrict__ G, const void* __restrict__ bl,
    const int* __restrict__ flag, float* __restrict__ Cst, float* __restrict__ Hst,
    const u16* __restrict__ outb, const int* __restrict__ batch,
    float* __restrict__ Rst, u16* __restrict__ Abuf, float* __restrict__ ebuf) {
    __shared__ __attribute__((aligned(16))) u16 Ls[GROWS * 256];
    __shared__ __attribute__((aligned(16))) float hsh[256];
    __shared__ float esh[GROWS];
    __shared__ float red[256];
    const int b = blockIdx.x, tid = threadIdx.x;
    const int w = tid >> 6, lane = tid & 63;
    const int f32 = flag[0];

    // LSTM cell for graph b (identical math to the old lstm_kernel)
    {
        float gi = G[b * 1024 + tid]       + ldv(bl, tid, f32);
        float gf = G[b * 1024 + 256 + tid] + ldv(bl, 256 + tid, f32);
        float gg = G[b * 1024 + 512 + tid] + ldv(bl, 512 + tid, f32);
        float go = G[b * 1024 + 768 + tid] + ldv(bl, 768 + tid, f32);
        float c = Cst[b * 256 + tid];
        c = sigm(gf) * c + sigm(gi) * tanhf(gg);
        Cst[b * 256 + tid] = c;
        float h = sigm(go) * tanhf(c);
        Hst[b * 256 + tid] = h;
        u16 hb = f2bu(h);
        Abuf[b * 768 + tid] = hb;
        Abuf[b * 768 + 512 + tid] = hb;
        hsh[tid] = h;
    }
    const int n0 = lower_bound(batch, 30000, b);
    const int n1 = lower_bound(batch, 30000, b + 1);
    const int cnt = n1 - n0;
    __syncthreads();
    float r_out = 0.0f;
    if (cnt > 0 && cnt <= GROWS) {
        for (int idx = tid; idx < cnt * 32; idx += 256) {
            int i = idx >> 5, c8 = idx & 31;
            *(s16x8*)(Ls + i * 256 + c8 * 8) = *(const s16x8*)(outb + (n0 + i) * 256 + c8 * 8);
        }
        __syncthreads();
        for (int i = w; i < cnt; i += 4) {
            s16x4 ov = *(const s16x4*)(Ls + i * 256 + lane * 4);
            f32x4 hv = *(const f32x4*)(hsh + lane * 4);
            float p = b2f((u16)ov[0]) * hv[0] + b2f((u16)ov[1]) * hv[1]
                    + b2f((u16)ov[2]) * hv[2] + b2f((u16)ov[3]) * hv[3];
            #pragma unroll
            for (int off = 1; off < 64; off <<= 1) p += __shfl_xor(p, off, 64);
            if (lane == 0) esh[i] = p;
        }
        __syncthreads();
        float m = -1e30f;
        for (int i = tid; i < cnt; i += 256) m = fmaxf(m, esh[i]);
        red[tid] = m; __syncthreads();
        for (int s = 128; s > 0; s >>= 1) { if (tid < s) red[tid] = fmaxf(red[tid], red[tid + s]); __syncthreads(); }
        m = red[0]; __syncthreads();
        float sl = 0.0f;
        for (int i = tid; i < cnt; i += 256) { float pe = expf(esh[i] - m); esh[i] = pe; sl += pe; }
        red[tid] = sl; __syncthreads();
        for (int s = 128; s > 0; s >>= 1) { if (tid < s) red[tid] += red[tid + s]; __syncthreads(); }
        float ssum = red[0]; __syncthreads();
        float acc = 0.0f;
        for (int i = 0; i < cnt; ++i) acc += esh[i] * b2f(Ls[i * 256 + tid]);
        r_out = acc / ssum;
    } else if (cnt > GROWS) {
        for (int i = w; i < cnt; i += 4) {
            const u16* orow = outb + (n0 + i) * 256 + lane * 4;
            f32x4 hv = *(const f32x4*)(hsh + lane * 4);
            float p = b2f(orow[0]) * hv[0] + b2f(orow[1]) * hv[1]
                    + b2f(orow[2]) * hv[2] + b2f(orow[3]) * hv[3];
            #pragma unroll
            for (int off = 1; off < 64; off <<= 1) p += __shfl_xor(p, off, 64);
            if (lane == 0) ebuf[n0 + i] = p;
        }
        __syncthreads();
        float m = -1e30f;
        for (int n = n0 + tid; n < n1; n += 256) m = fmaxf(m, ebuf[n]);
        red[tid] = m; __syncthreads();
        for (int s = 128; s > 0; s >>= 1) { if (tid < s) red[tid] = fmaxf(red[tid], red[tid + s]); __syncthreads(); }
        m = red[0]; __syncthreads();
        float sl = 0.0f;
        for (int n = n0 + tid; n < n1; n += 256) sl += expf(ebuf[n] - m);
        red[tid] = sl; __syncthreads();
        for (int s = 128; s > 0; s >>= 1) { if (tid < s) red[tid] += red[tid + s]; __syncthreads(); }
        float ssum = red[0]; __syncthreads();
        float acc = 0.0f;
        for (int c0 = n0; c0 < n1; c0 += 256) {
            int nn = n1 - c0; if (nn > 256) nn = 256;
            __syncthreads();
            if (tid < nn) red[tid] = expf(ebuf[c0 + tid] - m);
            __syncthreads();
            for (int i = 0; i < nn; ++i) acc += red[i] * b2f(outb[(c0 + i) * 256 + tid]);
        }
        r_out = acc / ssum;
    }
    Rst[b * 256 + tid] = r_out;
    Abuf[b * 768 + 256 + tid] = f2bu(r_out);
}

// ---- readout + stage diagnostics (agg format aware).
// LATENCY FIX: dtype branch hoisted OUT of the 512-deep k-loop; each
// specialized loop unrolled x8 so ~8 W1 loads are in flight per thread
// (was: branchy ldv -> 1 outstanding load -> ~90 us latency-bound).
// Single accumulator, same order -> bit-identical result. ----
__global__ __launch_bounds__(256) void readout_kernel(const float* Hst, const float* Rst,
                                                      const void* W1, const void* b1,
                                                      const void* W2, const void* b2,
                                                      const u16* nodeout, const void* aggV,
                                                      int agg_bf16,
                                                      const int* flag, void* out) {
    int f32 = flag[0];
    int b = blockIdx.x, tid = threadIdx.x;
    __shared__ float qs[512];
    __shared__ float red[256];
    qs[tid] = Hst[b * 256 + tid];
    qs[256 + tid] = Rst[b * 256 + tid];
    __syncthreads();
    float a = ldv(b1, tid, f32);
    if (f32) {
        const float* W1f = (const float*)W1;
        #pragma unroll 8
        for (int k = 0; k < 512; ++k) a += qs[k] * W1f[k * 256 + tid];
    } else {
        const u16* W1h = (const u16*)W1;
        #pragma unroll 8
        for (int k = 0; k < 512; ++k) a += qs[k] * b2f(W1h[k * 256 + tid]);
    }
    a = fmaxf(a, 0.0f) * ldv(W2, tid, f32);
    red[tid] = a; __syncthreads();
    for (int s = 128; s > 0; s >>= 1) { if (tid < s) red[tid] += red[tid + s]; __syncthreads(); }
    if (tid == 0) {
        float D = 0.0f;
        if (b == 0) {
            float s1 = 0.0f, s2 = 0.0f, s3 = 0.0f;
            for (int i = 0; i < 256; ++i) {
                s1 += fabsf(b2f(nodeout[i]));
                s2 += agg_bf16 ? fabsf(b2f(((const u16*)aggV)[i]))
                               : fabsf(((const float*)aggV)[i]);
                s3 += fabsf(Rst[i]);
            }
            if (s1 < 1e-3f) D += 100.0f;
            if (s2 < 1e-3f) D += 200.0f;
            if (s3 < 1e-6f) D += 400.0f;
        }
        stv(out, b, red[0] + ldv(b2, 0, f32) + D, f32);
    }
}

// ---------------- workspace layout (bytes) ----------------
// INVARIANT: Abuf and G alias the aggP region (workspace reuse). aggP's last
// readers are node_dual_kernel (+ readout diagnostics, first 512 B only);
// Abuf/G must only be written AFTER node_dual runs.
#define OFF_FLAG 0
#define OFF_HST  64
#define OFF_RST  524352
#define OFF_CST  1048640
#define OFF_PLO  64
#define OFF_PHI  960064
#define OFF_CUR  1440064
#define OFF_WREG 1572928
#define OFF_WM1B (OFF_WREG)
#define OFF_WM2B (OFF_WREG + 147456)
#define OFF_WRB  (OFF_WREG + 278528)
#define OFF_WCAT (OFF_WREG + 409600)
#define OFF_E    3670080
#define OFF_AGG  3790144
#define OFF_ABUF (OFF_AGG + 1048576)
#define OFF_G    (OFF_AGG + 4194304)
#define OFF_H0B  34510144
#define WS_NEEDED 49870144
#define OFF_Q    49870144                 // fast path: Q bf16 [30000x256]
#define WS_FAST  (49870144 + 15360000)
#define OFF_SRC  (OFF_Q + 15360000)       // fast2: src u16 per sorted edge
#define WS_FAST2 (OFF_SRC + 960000)

extern "C" __attribute__((visibility("default")))
void kernel_launch(void* const* d_in, const int* in_sizes, int n_in,
                   void* d_out, int out_size, void* d_ws, size_t ws_size,
                   hipStream_t stream) {
    char* ws = (char*)d_ws;
    int*   flag   = (int*)(ws + OFF_FLAG);
    float* Hst    = (float*)(ws + OFF_HST);
    float* Rst    = (float*)(ws + OFF_RST);
    float* Cst    = (float*)(ws + OFF_CST);
    u16*   permLo = (u16*)(ws + OFF_PLO);
    u8*    permHi = (u8*)(ws + OFF_PHI);
    u32*   cursor = (u32*)(ws + OFF_CUR);
    u16*   Wm1b   = (u16*)(ws + OFF_WM1B);
    u16*   Wm2b   = (u16*)(ws + OFF_WM2B);
    u16*   Wrb    = (u16*)(ws + OFF_WRB);
    u16*   Wcatb  = (u16*)(ws + OFF_WCAT);
    float* ebuf   = (float*)(ws + OFF_E);
    u32*   part   = (u32*)(ws + OFF_E);
    u32*   pexcl  = (u32*)(ws + OFF_E + 512);
    float* aggP   = (float*)(ws + OFF_AGG);
    u16*   Abuf   = (u16*)(ws + OFF_ABUF);
    float* G      = (float*)(ws + OFF_G);
    u16*   h0b    = (u16*)(ws + OFF_H0B);
    u16*   Qb     = (u16*)(ws + OFF_Q);
    u16*   srcW   = (u16*)(ws + OFF_SRC);

    detect_kernel<<<1, 256, 0, stream>>>(d_in[0], flag);

    bool sizes_ok = (n_in == 19)
        && in_sizes[0] == 30000 * 25
        && in_sizes[1] == 480000 * 14
        && in_sizes[4] == 270 * 256
        && in_sizes[10] == 512 * 1024
        && in_sizes[17] == 2 * 480000
        && in_sizes[18] == 30000;
    if (!sizes_ok) { fillv_kernel<<<2, 256, 0, stream>>>(d_out, flag, 1600.0f); return; }
    if (ws_size < (size_t)WS_NEEDED) { fillv_kernel<<<2, 256, 0, stream>>>(d_out, flag, 800.0f); return; }
    const int fastlvl = (ws_size >= (size_t)WS_FAST2) ? 2
                      : (ws_size >= (size_t)WS_FAST)  ? 1 : 0;

    fillv_kernel<<<2, 256, 0, stream>>>(d_out, flag, 3.0f);
    DMPNN_Change_678604832935_kernel<<<1, 64, 0, stream>>>((int*)(ws + OFF_G));

    const void* x     = d_in[0];
    const void* eattr = d_in[1];
    const void* W0    = d_in[2];
    const void* b0    = d_in[3];
    const void* Wm1   = d_in[4];
    const void* bm1   = d_in[5];
    const void* Wm2   = d_in[6];
    const void* bm2   = d_in[7];
    const void* Wr    = d_in[8];
    const void* br    = d_in[9];
    const void* Wih   = d_in[10];
    const void* Whh   = d_in[11];
    const void* bl    = d_in[12];
    const void* W1    = d_in[13];
    const void* b1    = d_in[14];
    const void* W2    = d_in[15];
    const void* b2    = d_in[16];
    const int* eidx   = (const int*)d_in[17];
    const int* batch  = (const int*)d_in[18];

    // all weight relayouts in one launch
    to_blocked_all<<<3872, 256, 0, stream>>>(Wm1, Wm2, Wr, Wih, Whh, flag,
                                             Wm1b, Wm2b, Wrb, Wcatb);

    if (fastlvl >= 1) {
        // fused lin0 + qgen (needs Wm1b + Qb space)
        lin0q_kernel<<<469, 256, 0, stream>>>(x, W0, b0, flag, Wm1b, h0b, Qb);
    } else {
        lin0_kernel<<<3750, 256, 0, stream>>>(x, W0, b0, flag, h0b);
    }

    // counting sort of edges by dst (CSR); integer atomics only
    zero_kernel<<<30, 256, 0, stream>>>((float*)cursor, 30000);
    hist_kernel<<<1875, 256, 0, stream>>>(eidx, cursor);
    scan1_kernel<<<118, 256, 0, stream>>>(cursor, part);
    scan2_kernel<<<1, 128, 0, stream>>>(part, pexcl, 118);
    scan3_kernel<<<118, 256, 0, stream>>>(cursor, pexcl);
    scatter_kernel<<<1875, 256, 0, stream>>>(eidx, cursor, permLo, permHi,
                                             (fastlvl == 2) ? srcW : (u16*)nullptr);

    int agg_bf16 = 0;
    if (fastlvl == 2) {
        agg_bf16 = 1;
        edge_mfma_node2_kernel<<<30000, 256, 0, stream>>>(Qb, eattr, srcW, permLo, permHi,
                                                          cursor, Wm1b, bm1, flag,
                                                          (u16*)aggP);
    } else if (fastlvl == 1) {
        edge_mfma_node_kernel<<<30000, 256, 0, stream>>>(Qb, eattr, eidx, permLo, permHi,
                                                         cursor, Wm1b, bm1, flag, aggP);
    } else {
        zero_kernel<<<1024, 256, 0, stream>>>(aggP, 7680000);
        edge_sorted_kernel<<<7500, 256, 0, stream>>>(h0b, eattr, eidx, permLo, permHi,
                                                     Wm1b, bm1, flag, aggP);
    }
    node_dual_kernel<<<469, 256, 0, stream>>>(h0b, Wrb, Wm2b, br, bm2,
                                              aggP, agg_bf16, cursor, flag);

    // zero Cst + Abuf AFTER node_dual: Abuf aliases the aggP region (invariant above)
    zero2_kernel<<<256, 256, 0, stream>>>(Cst, 131072, (float*)Abuf, 196608);

    for (int s = 0; s < 3; ++s) {
        gates_mfma_kernel<<<dim3(8, 16), 256, 0, stream>>>(Abuf, Wcatb, G);
        s2s_lstm_fused_kernel<<<512, 256, 0, stream>>>(G, bl, flag, Cst, Hst,
                                                       h0b, batch, Rst, Abuf, ebuf);
    }
    readout_kernel<<<512, 256, 0, stream>>>(Hst, Rst, W1, b1, W2, b2, h0b,
                                            aggP, agg_bf16, flag, d_out);
}